// Round 12
// baseline (212.133 us; speedup 1.0000x reference)
//
#include <hip/hip_runtime.h>

// ============================================================================
// EfficientAttention: x->(QKV proj)->LN(q)->flash attention->(+q)->out proj
// B=2, N=2048, D=1024, H=16, d=64.  bf16 MFMA pipeline, fp32 accumulate.
// R24: attention KVBLK 64->128 (two 64-key tiles per barrier): the kF/vF
//      frag-ordered layouts make a tile-pair a contiguous 16KB run, so the
//      stage stays a pure linear cp16 copy; barrier+vmcnt(0)-drain count
//      halves 32->16 (the m97-class ~20% stall, paid per barrier). LDS
//      64KB/block x 2 blocks/CU = 128KB <= 160KB: occupancy unchanged.
//      Plus T5 s_setprio(1) around each tile-compute (2 independent
//      blocks/CU = phase-diverse waves, the regime where attn +4-7%).
//      LN composition frozen (R21/R22/R23 spread 207.6-211.6 = noise):
//      separate full-LN kernel + plain attention. GEMMs/preprocess = R23.
// ============================================================================

typedef unsigned short u16;
typedef __attribute__((ext_vector_type(8))) short bf8v;   // 8 bf16 (bit-pattern shorts)
typedef __attribute__((ext_vector_type(4))) float f4v;    // MFMA acc

typedef __attribute__((address_space(1))) void gvoid;
typedef __attribute__((address_space(3))) void lvoid;
__device__ __forceinline__ void cp16(const void* g, void* l) {
  __builtin_amdgcn_global_load_lds((gvoid*)g, (lvoid*)l, 16, 0, 0);
}

__device__ __forceinline__ float bf2f(u16 u) {
  unsigned int x = ((unsigned int)u) << 16;
  float f; __builtin_memcpy(&f, &x, 4); return f;
}
__device__ __forceinline__ u16 f2bf(float f) {
  unsigned int x; __builtin_memcpy(&x, &f, 4);
  unsigned int r = (x + 0x7fffu + ((x >> 16) & 1u)) >> 16;   // RNE
  return (u16)r;
}
// pack 2 floats' bf16 truncations into one u32 (a -> low16, b -> high16)
__device__ __forceinline__ unsigned pack2bf(float a, float b) {
  unsigned ua, ub;
  __builtin_memcpy(&ua, &a, 4); __builtin_memcpy(&ub, &b, 4);
  return __builtin_amdgcn_perm(ub, ua, 0x07060302u);
}

#define KSCALE 0.18033688011f   // log2(e) / sqrt(64)

// ---------------------------------------------------------------------------
// Fused preprocessing: ONE launch does
//   blocks [0,2048):      x -> bf16 copy (self-classified)
//   blocks [2048,3072):   W0..W3 transpose to wt (self-classified)
//   block  3072:          the 11-tensor flags classifier
// ---------------------------------------------------------------------------
__global__ __launch_bounds__(256) void k_preprocess(
    const u16* a0, const u16* a1, const u16* a2, const u16* a3,
    const u16* a4, const u16* a5, const u16* a6, const u16* a7,
    const u16* a8, const u16* a9, const u16* a10,
    u16* xb, u16* wt, int* flags) {
  const int blk = blockIdx.x;
  const int t = threadIdx.x;
  __shared__ u16 tile[64 * 65];
  __shared__ int cls[3];

  if (blk >= 3072) {
    // ---- flags classifier ----
    if (t >= 11) return;
    const u16* arr[11] = {a0,a1,a2,a3,a4,a5,a6,a7,a8,a9,a10};
    const u16* p = arr[t];
    int ze = 0, no = 0, pe = 0;
    for (int i = 0; i < 128; ++i) {
      u16 he = p[2*i], ho = p[2*i+1];
      if (he == 0) ze++;
      if (ho != 0) no++;
      int e = (he >> 7) & 0xff;
      if (he == 0 || (e >= 64 && e <= 160)) pe++;
    }
    int isbf;
    if (ze >= 100 && no >= 64) isbf = 0;
    else isbf = (pe >= 100) ? 1 : 0;
    flags[t] = isbf;
    return;
  }

  // ---- self-classification of this block's source tensor ----
  int wz = (blk - 2048) >> 8;                       // W index (transpose blocks)
  const u16* src = (blk < 2048) ? a0
                 : (wz == 0) ? a1 : (wz == 1) ? a3 : (wz == 2) ? a5 : a7;
  if (t == 0) { cls[0] = 0; cls[1] = 0; cls[2] = 0; }
  __syncthreads();
  if (t < 128) {
    u16 he = src[2*t], ho = src[2*t+1];
    int e = (he >> 7) & 0xff;
    if (he == 0) atomicAdd(&cls[0], 1);
    if (ho != 0) atomicAdd(&cls[1], 1);
    if (he == 0 || (e >= 64 && e <= 160)) atomicAdd(&cls[2], 1);
  }
  __syncthreads();
  int isbf;
  if (cls[0] >= 100 && cls[1] >= 64) isbf = 0;
  else isbf = (cls[2] >= 100) ? 1 : 0;

  if (blk < 2048) {
    // ---- convert x -> bf16 (8 elems/thread) ----
    size_t i = ((size_t)blk * 256 + t) * 8;
    if (isbf) {
      *(float4*)(xb + i) = *((const float4*)(a0 + i));
    } else {
      const float* xf = (const float*)a0;
      float4 a = *(const float4*)(xf + i);
      float4 b = *(const float4*)(xf + i + 4);
      ushort4 o0, o1;
      o0.x = f2bf(a.x); o0.y = f2bf(a.y); o0.z = f2bf(a.z); o0.w = f2bf(a.w);
      o1.x = f2bf(b.x); o1.y = f2bf(b.y); o1.z = f2bf(b.z); o1.w = f2bf(b.w);
      *(ushort4*)(xb + i) = o0; *(ushort4*)(xb + i + 4) = o1;
    }
    return;
  }

  // ---- transpose W[wz]: 64x64 tile (pad 65 => 2-way banks) ----
  {
    int rem = (blk - 2048) & 255;
    int r0 = ((rem >> 4) & 15) * 64, c0 = (rem & 15) * 64;
    u16* dst = wt + (size_t)wz * (1u << 20);
    for (int rr = 0; rr < 2; ++rr) {
      int row = rr * 32 + (t >> 3);
      int c8 = (t & 7) * 8;
      u16 v[8];
      if (isbf) {
        const u16* Ws = src;
        ushort4 a = *(const ushort4*)&Ws[(size_t)(r0 + row) * 1024 + c0 + c8];
        ushort4 b = *(const ushort4*)&Ws[(size_t)(r0 + row) * 1024 + c0 + c8 + 4];
        v[0]=a.x; v[1]=a.y; v[2]=a.z; v[3]=a.w; v[4]=b.x; v[5]=b.y; v[6]=b.z; v[7]=b.w;
      } else {
        const float* Wf = (const float*)src;
        float4 a = *(const float4*)&Wf[(size_t)(r0 + row) * 1024 + c0 + c8];
        float4 b = *(const float4*)&Wf[(size_t)(r0 + row) * 1024 + c0 + c8 + 4];
        v[0]=f2bf(a.x); v[1]=f2bf(a.y); v[2]=f2bf(a.z); v[3]=f2bf(a.w);
        v[4]=f2bf(b.x); v[5]=f2bf(b.y); v[6]=f2bf(b.z); v[7]=f2bf(b.w);
      }
#pragma unroll
      for (int j = 0; j < 8; ++j) tile[row * 65 + c8 + j] = v[j];
    }
    __syncthreads();
    for (int rr = 0; rr < 2; ++rr) {
      int nrow = rr * 32 + (t >> 3);
      int k8 = (t & 7) * 8;
      u16 v[8];
#pragma unroll
      for (int j = 0; j < 8; ++j) v[j] = tile[(k8 + j) * 65 + nrow];
      ushort4 o0, o1;
      o0.x=v[0]; o0.y=v[1]; o0.z=v[2]; o0.w=v[3];
      o1.x=v[4]; o1.y=v[5]; o1.z=v[6]; o1.w=v[7];
      *(ushort4*)&dst[(size_t)(c0 + nrow) * 1024 + r0 + k8] = o0;
      *(ushort4*)&dst[(size_t)(c0 + nrow) * 1024 + r0 + k8 + 4] = o1;
    }
  }
}

// ---------------------------------------------------------------------------
// MTx128-tile gemm_bt: C[m0..m0+MT, n0..n0+128] = A @ Bt^T + bias
// BK=32, double-buffered LDS, ONE barrier per K-iter.
// mode: 0 = fp32 rowmajor, 1 = bf16 rowmajor, 2 = bf16 scatter to vF,
//       3 = bf16 scatter to kF (fragment-ordered K for LDS-staged attention)
// ---------------------------------------------------------------------------
template <int MT>
__device__ __forceinline__ void gemm_bt(const u16* __restrict__ A, const u16* __restrict__ Bt,
    const void* __restrict__ bias, int bias_bf, void* __restrict__ Cout, int mode,
    float cscale, int m0, int n0) {
  constexpr int MI = MT / 32;                             // acc row-tiles per wave
  __shared__ __align__(16) u16 As[2][MT * 32];
  __shared__ __align__(16) u16 Bs[2][128 * 32];
  const int tid = threadIdx.x;
  const int wave = tid >> 6, lane = tid & 63;
  const int qd = lane >> 4, ln = lane & 15;
  const int wr = (wave >> 1) * (MT / 2), wc = (wave & 1) * 64;
  const int r0 = wave * 16 + (lane >> 2);
  const int csrc = ((lane & 3) ^ ((lane >> 2) & 3)) * 8;  // swizzled src chunk
  const u16* Ag = &A[(size_t)m0 * 1024];
  const u16* Bg = &Bt[(size_t)n0 * 1024];
  const int co = (qd ^ (ln & 3)) * 8;                     // frag-read chunk
  f4v acc[MI][4];
#pragma unroll
  for (int i = 0; i < MI; ++i)
#pragma unroll
    for (int j = 0; j < 4; ++j) acc[i][j] = (f4v){0.f, 0.f, 0.f, 0.f};

#pragma unroll
  for (int t = 0; t < MT / 64; ++t)
    cp16(&Ag[(size_t)(t * 64 + r0) * 1024 + csrc], &As[0][(t * 256 + wave * 64) * 8]);
#pragma unroll
  for (int t = 0; t < 2; ++t)
    cp16(&Bg[(size_t)(t * 64 + r0) * 1024 + csrc], &Bs[0][(t * 256 + wave * 64) * 8]);

  for (int it = 0; it < 32; ++it) {
    __syncthreads();                       // drains stage(it) (issued last iter)
    if (it < 31) {
      int ko = (it + 1) * 32;
      int bi = (it + 1) & 1;
#pragma unroll
      for (int t = 0; t < MT / 64; ++t)
        cp16(&Ag[(size_t)(t * 64 + r0) * 1024 + ko + csrc], &As[bi][(t * 256 + wave * 64) * 8]);
#pragma unroll
      for (int t = 0; t < 2; ++t)
        cp16(&Bg[(size_t)(t * 64 + r0) * 1024 + ko + csrc], &Bs[bi][(t * 256 + wave * 64) * 8]);
    }
    const u16* as = As[it & 1];
    const u16* bs = Bs[it & 1];
    bf8v af[MI], bfr[4];
#pragma unroll
    for (int i = 0; i < MI; ++i) af[i]  = *(const bf8v*)&as[(wr + i * 16 + ln) * 32 + co];
#pragma unroll
    for (int j = 0; j < 4; ++j) bfr[j] = *(const bf8v*)&bs[(wc + j * 16 + ln) * 32 + co];
#pragma unroll
    for (int i = 0; i < MI; ++i)
#pragma unroll
      for (int j = 0; j < 4; ++j)
        acc[i][j] = __builtin_amdgcn_mfma_f32_16x16x32_bf16(af[i], bfr[j], acc[i][j], 0, 0, 0);
  }
  // epilogue: C row = m0+wr+i*16+qd*4+r, col = n0+wc+j*16+ln
#pragma unroll
  for (int j = 0; j < 4; ++j) {
    int col = n0 + wc + j * 16 + ln;
    float bv = bias_bf ? bf2f(((const u16*)bias)[col]) : ((const float*)bias)[col];
#pragma unroll
    for (int i = 0; i < MI; ++i) {
      int row = m0 + wr + i * 16 + qd * 4;
      if (mode == 2) {
        // scatter to vF[bh][kt][c][dt][lane(qd_f*16+ln_f)][8]
        ushort4 o4;
        o4.x = f2bf((acc[i][j][0] + bv) * cscale);
        o4.y = f2bf((acc[i][j][1] + bv) * cscale);
        o4.z = f2bf((acc[i][j][2] + bv) * cscale);
        o4.w = f2bf((acc[i][j][3] + bv) * cscale);
        int b_ = row >> 11, nl = row & 2047;
        int h_ = col >> 6, d6 = col & 63;
        int kt = nl >> 6, b0 = nl & 63;
        int c = b0 >> 5, g = (b0 >> 4) & 1, qd_f = (b0 >> 2) & 3;
        int dt = d6 >> 4, ln_f = d6 & 15;
        size_t off = (size_t)(b_ * 16 + h_) * 131072
                   + (size_t)(kt * 4096 + (c * 4 + dt) * 512 + (qd_f * 16 + ln_f) * 8 + g * 4);
        *(ushort4*)&((u16*)Cout)[off] = o4;
      } else if (mode == 3) {
        // scatter to kF[bh][tile][ct*2+half][lane(qd_k*16+ln_k)][8]
        int b_ = row >> 11, nl = row & 2047;
        int h_ = col >> 6, d6 = col & 63;
        int tile = nl >> 6, ct = (nl >> 4) & 3;
        int half = d6 >> 5, qd_k = (d6 >> 3) & 3, jj = d6 & 7;
        size_t base = (size_t)(b_ * 16 + h_) * 131072
                    + (size_t)(tile * 4096 + (ct * 2 + half) * 512 + qd_k * 128 + jj);
#pragma unroll
        for (int r = 0; r < 4; ++r) {
          float v = (acc[i][j][r] + bv) * cscale;
          ((u16*)Cout)[base + (size_t)(((nl & 15) + r) * 8)] = f2bf(v);
        }
      } else {
#pragma unroll
        for (int r = 0; r < 4; ++r) {
          float v = (acc[i][j][r] + bv) * cscale;
          if (mode == 1) ((u16*)Cout)[(size_t)(row + r) * 1024 + col] = f2bf(v);
          else           ((float*)Cout)[(size_t)(row + r) * 1024 + col] = v;
        }
      }
    }
  }
}

// 1D grid 768, XCD-chunk swizzled: HW XCD = id%8. XCD k owns y-chunk (k>>1)
// (8 m-tiles) x x-chunk (k&1) (4 n-tiles) x all z. Within-XCD order: x
// innermost, then z, then y -> 12 consecutive blocks share one A panel.
__global__ __launch_bounds__(256) void k_gemm_qkv(const u16* xb, const u16* wt,
    const void* bq, const void* bk, const void* bv, const int* flags,
    u16* qpre, u16* kb, u16* vtb) {
  const int id = blockIdx.x;
  const int xcd = id & 7, j = id >> 3;    // j in [0,96)
  const int xw = j & 3, jj = j >> 2;      // jj in [0,24)
  const int z = jj % 3, yw = jj / 3;      // yw in [0,8)
  const int y = (xcd >> 1) * 8 + yw;      // m-tile in [0,32)
  const int x = (xcd & 1) * 4 + xw;       // n-tile in [0,8)
  const u16* Bt = wt + (size_t)z * (1u << 20);
  const void* bias = (z == 0) ? bq : (z == 1) ? bk : bv;
  if (z == 0)      gemm_bt<128>(xb, Bt, bias, flags[2], qpre, 1, 1.0f,   y * 128, x * 128);
  else if (z == 1) gemm_bt<128>(xb, Bt, bias, flags[4], kb,   3, KSCALE, y * 128, x * 128);
  else             gemm_bt<128>(xb, Bt, bias, flags[6], vtb,  2, 1.0f,   y * 128, x * 128);
}

// 1D grid 512, same swizzle idea: XCD k owns y-chunk (k>>1) (16 m-tiles of
// 64) x x-chunk (k&1) (4 n-tiles).
__global__ __launch_bounds__(256) void k_gemm_out(const u16* A, const u16* Bt,
    const void* bias, const int* flags, void* out) {
  const int id = blockIdx.x;
  const int xcd = id & 7, j = id >> 3;    // j in [0,64)
  const int xw = j & 3, yw = j >> 2;      // yw in [0,16)
  const int y = (xcd >> 1) * 16 + yw;     // m-tile in [0,64)
  const int x = (xcd & 1) * 4 + xw;       // n-tile in [0,8)
  gemm_bt<64>(A, Bt, bias, flags[8], out, flags[0] ? 1 : 0, 1.0f, y * 64, x * 128);
}

// ---------------------------------------------------------------------------
// LayerNorm over rows of 1024: block per row, 256 threads x 4 elems.
// (Separate-kernel form: fusing LN into attention cost ~10us — R21/R22.)
// ---------------------------------------------------------------------------
__global__ __launch_bounds__(256) void k_layernorm(const u16* __restrict__ qp,
    const void* __restrict__ g, const void* __restrict__ bb, const int* flags,
    u16* __restrict__ out) {
  int row = blockIdx.x, t = threadIdx.x;
  const u16* rp = qp + (size_t)row * 1024;
  ushort4 u = *(const ushort4*)(rp + t * 4);
  float x0 = bf2f(u.x), x1 = bf2f(u.y), x2 = bf2f(u.z), x3 = bf2f(u.w);
  float s = x0 + x1 + x2 + x3;
  float s2 = x0 * x0 + x1 * x1 + x2 * x2 + x3 * x3;
  for (int off = 32; off; off >>= 1) { s += __shfl_down(s, off); s2 += __shfl_down(s2, off); }
  __shared__ float red[10];
  int wave = t >> 6, lane = t & 63;
  if (lane == 0) { red[wave] = s; red[4 + wave] = s2; }
  __syncthreads();
  if (t == 0) {
    float S = red[0] + red[1] + red[2] + red[3];
    float S2 = red[4] + red[5] + red[6] + red[7];
    float mu = S * (1.f / 1024.f);
    float var = S2 * (1.f / 1024.f) - mu * mu;
    red[8] = mu; red[9] = rsqrtf(var + 1e-5f);
  }
  __syncthreads();
  float mu = red[8], rstd = red[9];
  int gf = flags[9], bf = flags[10];
  int c = t * 4;
  float gv[4], bv[4];
#pragma unroll
  for (int k = 0; k < 4; ++k) {
    gv[k] = gf ? bf2f(((const u16*)g)[c + k]) : ((const float*)g)[c + k];
    bv[k] = bf ? bf2f(((const u16*)bb)[c + k]) : ((const float*)bb)[c + k];
  }
  ushort4 o;
  o.x = f2bf((x0 - mu) * rstd * gv[0] + bv[0]);
  o.y = f2bf((x1 - mu) * rstd * gv[1] + bv[1]);
  o.z = f2bf((x2 - mu) * rstd * gv[2] + bv[2]);
  o.w = f2bf((x3 - mu) * rstd * gv[3] + bv[3]);
  *(ushort4*)(out + (size_t)row * 1024 + c) = o;
}

// ---------------------------------------------------------------------------
// One-tile attention compute from LDS-resident fragments (all static idx).
// ---------------------------------------------------------------------------
template <int NQS>
__device__ __forceinline__ void attn_tile(const bf8v kf[4][2], const bf8v vf[8],
    const bf8v qf[NQS][2], float ls[NQS][4], f4v o[NQS][4]) {
#pragma unroll
  for (int qs = 0; qs < NQS; ++qs) {
    unsigned pk[4][2];
#pragma unroll
    for (int ct = 0; ct < 4; ++ct) {
      f4v z = (f4v){0.f, 0.f, 0.f, 0.f};
      z = __builtin_amdgcn_mfma_f32_16x16x32_bf16(kf[ct][0], qf[qs][0], z, 0, 0, 0);  // S^T
      z = __builtin_amdgcn_mfma_f32_16x16x32_bf16(kf[ct][1], qf[qs][1], z, 0, 0, 0);
      float p0 = __builtin_amdgcn_exp2f(z[0]);
      float p1 = __builtin_amdgcn_exp2f(z[1]);
      float p2 = __builtin_amdgcn_exp2f(z[2]);
      float p3 = __builtin_amdgcn_exp2f(z[3]);
      ls[qs][0] += p0; ls[qs][1] += p1; ls[qs][2] += p2; ls[qs][3] += p3;
      pk[ct][0] = pack2bf(p0, p1);
      pk[ct][1] = pack2bf(p2, p3);
    }
#pragma unroll
    for (int c = 0; c < 2; ++c) {
      unsigned avals[4] = {pk[2*c][0], pk[2*c][1], pk[2*c+1][0], pk[2*c+1][1]};
      bf8v af; __builtin_memcpy(&af, avals, 16);
#pragma unroll
      for (int dt = 0; dt < 4; ++dt)
        o[qs][dt] = __builtin_amdgcn_mfma_f32_16x16x32_bf16(af, vf[c * 4 + dt], o[qs][dt], 0, 0, 0);
    }
  }
}

// ---------------------------------------------------------------------------
// Flash attention: 256-thread blocks (4 waves), each wave 32 q-rows.
// R24: KVBLK=128 -- TWO 64-key tiles staged per barrier. kF/vF tile-pairs
// are contiguous 16KB runs, so each stage is 2 linear cp16 sweeps (K-pair,
// V-pair); barrier/drain count 32 -> 16. LDS 64KB/block, 2 blocks/CU ->
// 128KB/CU, occupancy unchanged (2 waves/SIMD). s_setprio(1) wraps each
// tile-compute (phase-diverse blocks on a CU -> scheduler favors MFMA wave).
// Grid 512 = XCD slot x 4 bh x 16 q-chunks; residual fused into store.
// ---------------------------------------------------------------------------
__global__ __launch_bounds__(256) void k_attention(const u16* __restrict__ qln,
    const u16* __restrict__ kfg, const u16* __restrict__ vfg, u16* __restrict__ attn) {
  const int x = blockIdx.x;
  const int xcd = x & 7, sl = x >> 3;                // sl in [0,64)
  const int bh = xcd * 4 + (sl >> 4), qc = sl & 15;  // 4 bh per XCD slot, 16 q-chunks
  const int b = bh >> 4, h = bh & 15;
  const int tid = threadIdx.x, wave = tid >> 6, lane = tid & 63;
  const int qd = lane >> 4, ln = lane & 15;
  const int qrow0 = qc * 128 + wave * 32;            // this wave's 32 q-rows

  const u16* kgb = kfg + (size_t)bh * 131072;        // kF fragment-ordered
  const u16* vgb = vfg + (size_t)bh * 131072;        // vF fragment-ordered

  __shared__ __align__(16) u16 kv[2][16384];         // [buf][K-pair 8192 | V-pair 8192]

  bf8v qf[2][2];
#pragma unroll
  for (int qs = 0; qs < 2; ++qs) {
    const u16* qb = qln + ((size_t)b * 2048 + qrow0 + qs * 16 + ln) * 1024 + h * 64;
    qf[qs][0] = *(const bf8v*)(qb + qd * 8);
    qf[qs][1] = *(const bf8v*)(qb + 32 + qd * 8);
  }
  float ls[2][4];
  f4v o[2][4];
#pragma unroll
  for (int qs = 0; qs < 2; ++qs)
#pragma unroll
    for (int r = 0; r < 4; ++r) { ls[qs][r] = 0.f; o[qs][r] = (f4v){0.f, 0.f, 0.f, 0.f}; }

  // prologue: stage tile-pair 0 (tiles 0,1) into buf 0: 8 cp16/thread = 32KB
#pragma unroll
  for (int q = 0; q < 4; ++q) {
    cp16(kgb + (size_t)(q * 256 + tid) * 8, &kv[0][(q * 256 + wave * 64) * 8]);
    cp16(vgb + (size_t)(q * 256 + tid) * 8, &kv[0][8192 + (q * 256 + wave * 64) * 8]);
  }

  for (int tp = 0; tp < 16; ++tp) {
    __syncthreads();                                 // drains stage(tp)
    if (tp < 15) {
      const u16* ks = kgb + (size_t)(tp + 1) * 8192;
      const u16* vs = vgb + (size_t)(tp + 1) * 8192;
      u16* dst = kv[(tp + 1) & 1];
#pragma unroll
      for (int q = 0; q < 4; ++q) {
        cp16(ks + (size_t)(q * 256 + tid) * 8, &dst[(q * 256 + wave * 64) * 8]);
        cp16(vs + (size_t)(q * 256 + tid) * 8, &dst[8192 + (q * 256 + wave * 64) * 8]);
      }
    }
    const u16* kvb = kv[tp & 1];
#pragma unroll
    for (int s = 0; s < 2; ++s) {                    // two 64-key tiles per pair
      const u16* kp = kvb + s * 4096;
      const u16* vp = kvb + 8192 + s * 4096;
      bf8v kfr[4][2], vfr[8];
#pragma unroll
      for (int ct = 0; ct < 4; ++ct) {
        kfr[ct][0] = *(const bf8v*)&kp[(ct * 2 + 0) * 512 + lane * 8];
        kfr[ct][1] = *(const bf8v*)&kp[(ct * 2 + 1) * 512 + lane * 8];
      }
#pragma unroll
      for (int cd = 0; cd < 8; ++cd)
        vfr[cd] = *(const bf8v*)&vp[cd * 512 + lane * 8];
      __builtin_amdgcn_s_setprio(1);
      attn_tile<2>(kfr, vfr, qf, ls, o);
      __builtin_amdgcn_s_setprio(0);
    }
  }

  // per q-subtile: reduce den (2 shuffles), store with fused residual
#pragma unroll
  for (int qs = 0; qs < 2; ++qs) {
    float lsum = (ls[qs][0] + ls[qs][1]) + (ls[qs][2] + ls[qs][3]);
    lsum += __shfl_xor(lsum, 16);
    lsum += __shfl_xor(lsum, 32);                     // den[q=ln] on every lane
    float rden[4];
#pragma unroll
    for (int r = 0; r < 4; ++r) {
      float dv = __shfl(lsum, (lane & 48) + qd * 4 + r);  // lane with ln=qd*4+r
      rden[r] = __builtin_amdgcn_rcpf(1e-8f + dv);
    }
#pragma unroll
    for (int dt = 0; dt < 4; ++dt) {
#pragma unroll
      for (int r = 0; r < 4; ++r) {
        size_t idx = ((size_t)b * 2048 + qrow0 + qs * 16 + qd * 4 + r) * 1024
                   + h * 64 + dt * 16 + ln;
        float val = o[qs][dt][r] * rden[r] + bf2f(qln[idx]);
        attn[idx] = f2bf(val);
      }
    }
  }
}

// ---------------------------------------------------------------------------
extern "C" void kernel_launch(void* const* d_in, const int* in_sizes, int n_in,
                              void* d_out, int out_size, void* d_ws, size_t ws_size,
                              hipStream_t stream) {
  // inputs: 0:x 1:Wq 2:bq 3:Wk 4:bk 5:Wv 6:bv 7:Wo 8:bo 9:ln_g 10:ln_b
  int* flags = (int*)d_ws;
  u16* base = (u16*)((char*)d_ws + 256);
  const size_t M1 = 1u << 20;
  u16* xb   = base;            // x bf16; overwritten by qln after gemm_qkv
  u16* wt   = base + 4 * M1;   // Wq^T,Wk^T,Wv^T,Wo^T (4 x 1M)
  u16* qpre = base + 8 * M1;   // q pre-LN; reused as attn-out after LN
  u16* kb   = base + 12 * M1;  // kF fragment-ordered K (pre-scaled by KSCALE)
  u16* vtb  = base + 16 * M1;  // vF fragment-ordered V (written by V-GEMM)
  u16* qln = xb;
  u16* at  = qpre;

  k_preprocess<<<3073, 256, 0, stream>>>(
      (const u16*)d_in[0], (const u16*)d_in[1], (const u16*)d_in[2], (const u16*)d_in[3],
      (const u16*)d_in[4], (const u16*)d_in[5], (const u16*)d_in[6], (const u16*)d_in[7],
      (const u16*)d_in[8], (const u16*)d_in[9], (const u16*)d_in[10], xb, wt, flags);
  k_gemm_qkv<<<768, 256, 0, stream>>>(xb, wt, d_in[2], d_in[4], d_in[6], flags,
                                      qpre, kb, vtb);
  k_layernorm<<<4096, 256, 0, stream>>>(qpre, d_in[9], d_in[10], flags, qln);
  k_attention<<<512, 256, 0, stream>>>(qln, kb, vtb, at);
  k_gemm_out<<<512, 256, 0, stream>>>(at, wt + 3 * M1, d_in[8], flags, d_out);
}

// Round 14
// 209.282 us; speedup vs baseline: 1.0136x; 1.0136x over previous
//
#include <hip/hip_runtime.h>

// ============================================================================
// EfficientAttention: x->(QKV proj)->LN(q)->flash attention->(+q)->out proj
// B=2, N=2048, D=1024, H=16, d=64.  bf16 MFMA pipeline, fp32 accumulate.
// R26 == R25 resubmitted (previous bench died with "container failed twice"
//      -- infra, not kernel: code re-audited for LDS/global OOB and mapping
//      correctness, no fault vector found).
// R25: qkv GEMM epilogue scatter fix. The kF (mode 3) epilogue issued 64
//      scalar 2B global stores/thread (~3% store efficiency) and vF (mode 2)
//      16 half-dense 8B scatters -- the prime suspect for the ~67us gap
//      between modeled dispatch costs and the measured pipeline. New path:
//      after the K-loop, write biased/scaled bf16 results to a 128x128 LDS
//      tile T (reuses the 32KB staging buffers exactly -- no occupancy
//      change), barrier, then 8 fully-coalesced 16B stores per thread in
//      kF/vF fragment order. Attention frozen at R24 (46.7us floor). LN
//      separate (R23). Swizzles unchanged.
// ============================================================================

typedef unsigned short u16;
typedef __attribute__((ext_vector_type(8))) short bf8v;   // 8 bf16 (bit-pattern shorts)
typedef __attribute__((ext_vector_type(4))) float f4v;    // MFMA acc

typedef __attribute__((address_space(1))) void gvoid;
typedef __attribute__((address_space(3))) void lvoid;
__device__ __forceinline__ void cp16(const void* g, void* l) {
  __builtin_amdgcn_global_load_lds((gvoid*)g, (lvoid*)l, 16, 0, 0);
}

__device__ __forceinline__ float bf2f(u16 u) {
  unsigned int x = ((unsigned int)u) << 16;
  float f; __builtin_memcpy(&f, &x, 4); return f;
}
__device__ __forceinline__ u16 f2bf(float f) {
  unsigned int x; __builtin_memcpy(&x, &f, 4);
  unsigned int r = (x + 0x7fffu + ((x >> 16) & 1u)) >> 16;   // RNE
  return (u16)r;
}
// pack 2 floats' bf16 truncations into one u32 (a -> low16, b -> high16)
__device__ __forceinline__ unsigned pack2bf(float a, float b) {
  unsigned ua, ub;
  __builtin_memcpy(&ua, &a, 4); __builtin_memcpy(&ub, &b, 4);
  return __builtin_amdgcn_perm(ub, ua, 0x07060302u);
}

#define KSCALE 0.18033688011f   // log2(e) / sqrt(64)

// ---------------------------------------------------------------------------
// Fused preprocessing: ONE launch does
//   blocks [0,2048):      x -> bf16 copy (self-classified)
//   blocks [2048,3072):   W0..W3 transpose to wt (self-classified)
//   block  3072:          the 11-tensor flags classifier
// ---------------------------------------------------------------------------
__global__ __launch_bounds__(256) void k_preprocess(
    const u16* a0, const u16* a1, const u16* a2, const u16* a3,
    const u16* a4, const u16* a5, const u16* a6, const u16* a7,
    const u16* a8, const u16* a9, const u16* a10,
    u16* xb, u16* wt, int* flags) {
  const int blk = blockIdx.x;
  const int t = threadIdx.x;
  __shared__ u16 tile[64 * 65];
  __shared__ int cls[3];

  if (blk >= 3072) {
    // ---- flags classifier ----
    if (t >= 11) return;
    const u16* arr[11] = {a0,a1,a2,a3,a4,a5,a6,a7,a8,a9,a10};
    const u16* p = arr[t];
    int ze = 0, no = 0, pe = 0;
    for (int i = 0; i < 128; ++i) {
      u16 he = p[2*i], ho = p[2*i+1];
      if (he == 0) ze++;
      if (ho != 0) no++;
      int e = (he >> 7) & 0xff;
      if (he == 0 || (e >= 64 && e <= 160)) pe++;
    }
    int isbf;
    if (ze >= 100 && no >= 64) isbf = 0;
    else isbf = (pe >= 100) ? 1 : 0;
    flags[t] = isbf;
    return;
  }

  // ---- self-classification of this block's source tensor ----
  int wz = (blk - 2048) >> 8;                       // W index (transpose blocks)
  const u16* src = (blk < 2048) ? a0
                 : (wz == 0) ? a1 : (wz == 1) ? a3 : (wz == 2) ? a5 : a7;
  if (t == 0) { cls[0] = 0; cls[1] = 0; cls[2] = 0; }
  __syncthreads();
  if (t < 128) {
    u16 he = src[2*t], ho = src[2*t+1];
    int e = (he >> 7) & 0xff;
    if (he == 0) atomicAdd(&cls[0], 1);
    if (ho != 0) atomicAdd(&cls[1], 1);
    if (he == 0 || (e >= 64 && e <= 160)) atomicAdd(&cls[2], 1);
  }
  __syncthreads();
  int isbf;
  if (cls[0] >= 100 && cls[1] >= 64) isbf = 0;
  else isbf = (cls[2] >= 100) ? 1 : 0;

  if (blk < 2048) {
    // ---- convert x -> bf16 (8 elems/thread) ----
    size_t i = ((size_t)blk * 256 + t) * 8;
    if (isbf) {
      *(float4*)(xb + i) = *((const float4*)(a0 + i));
    } else {
      const float* xf = (const float*)a0;
      float4 a = *(const float4*)(xf + i);
      float4 b = *(const float4*)(xf + i + 4);
      ushort4 o0, o1;
      o0.x = f2bf(a.x); o0.y = f2bf(a.y); o0.z = f2bf(a.z); o0.w = f2bf(a.w);
      o1.x = f2bf(b.x); o1.y = f2bf(b.y); o1.z = f2bf(b.z); o1.w = f2bf(b.w);
      *(ushort4*)(xb + i) = o0; *(ushort4*)(xb + i + 4) = o1;
    }
    return;
  }

  // ---- transpose W[wz]: 64x64 tile (pad 65 => 2-way banks) ----
  {
    int rem = (blk - 2048) & 255;
    int r0 = ((rem >> 4) & 15) * 64, c0 = (rem & 15) * 64;
    u16* dst = wt + (size_t)wz * (1u << 20);
    for (int rr = 0; rr < 2; ++rr) {
      int row = rr * 32 + (t >> 3);
      int c8 = (t & 7) * 8;
      u16 v[8];
      if (isbf) {
        const u16* Ws = src;
        ushort4 a = *(const ushort4*)&Ws[(size_t)(r0 + row) * 1024 + c0 + c8];
        ushort4 b = *(const ushort4*)&Ws[(size_t)(r0 + row) * 1024 + c0 + c8 + 4];
        v[0]=a.x; v[1]=a.y; v[2]=a.z; v[3]=a.w; v[4]=b.x; v[5]=b.y; v[6]=b.z; v[7]=b.w;
      } else {
        const float* Wf = (const float*)src;
        float4 a = *(const float4*)&Wf[(size_t)(r0 + row) * 1024 + c0 + c8];
        float4 b = *(const float4*)&Wf[(size_t)(r0 + row) * 1024 + c0 + c8 + 4];
        v[0]=f2bf(a.x); v[1]=f2bf(a.y); v[2]=f2bf(a.z); v[3]=f2bf(a.w);
        v[4]=f2bf(b.x); v[5]=f2bf(b.y); v[6]=f2bf(b.z); v[7]=f2bf(b.w);
      }
#pragma unroll
      for (int j = 0; j < 8; ++j) tile[row * 65 + c8 + j] = v[j];
    }
    __syncthreads();
    for (int rr = 0; rr < 2; ++rr) {
      int nrow = rr * 32 + (t >> 3);
      int k8 = (t & 7) * 8;
      u16 v[8];
#pragma unroll
      for (int j = 0; j < 8; ++j) v[j] = tile[(k8 + j) * 65 + nrow];
      ushort4 o0, o1;
      o0.x=v[0]; o0.y=v[1]; o0.z=v[2]; o0.w=v[3];
      o1.x=v[4]; o1.y=v[5]; o1.z=v[6]; o1.w=v[7];
      *(ushort4*)&dst[(size_t)(c0 + nrow) * 1024 + r0 + k8] = o0;
      *(ushort4*)&dst[(size_t)(c0 + nrow) * 1024 + r0 + k8 + 4] = o1;
    }
  }
}

// ---------------------------------------------------------------------------
// MTx128-tile gemm_bt: C[m0..m0+MT, n0..n0+128] = A @ Bt^T + bias
// BK=32, double-buffered LDS, ONE barrier per K-iter.
// mode: 0 = fp32 rowmajor, 1 = bf16 rowmajor,
//       2 = bf16 -> vF via LDS-bounce (coalesced 16B stores),
//       3 = bf16 -> kF via LDS-bounce (coalesced 16B stores)
// Modes 2/3 require MT == 128 (the bounce tile T reuses the 32KB staging
// LDS exactly).
// ---------------------------------------------------------------------------
template <int MT>
__device__ __forceinline__ void gemm_bt(const u16* __restrict__ A, const u16* __restrict__ Bt,
    const void* __restrict__ bias, int bias_bf, void* __restrict__ Cout, int mode,
    float cscale, int m0, int n0) {
  constexpr int MI = MT / 32;                             // acc row-tiles per wave
  __shared__ __align__(16) u16 smem[2][(MT + 128) * 32];  // [buf][As MT*32 | Bs 128*32]
  const int tid = threadIdx.x;
  const int wave = tid >> 6, lane = tid & 63;
  const int qd = lane >> 4, ln = lane & 15;
  const int wr = (wave >> 1) * (MT / 2), wc = (wave & 1) * 64;
  const int r0 = wave * 16 + (lane >> 2);
  const int csrc = ((lane & 3) ^ ((lane >> 2) & 3)) * 8;  // swizzled src chunk
  const u16* Ag = &A[(size_t)m0 * 1024];
  const u16* Bg = &Bt[(size_t)n0 * 1024];
  const int co = (qd ^ (ln & 3)) * 8;                     // frag-read chunk
  f4v acc[MI][4];
#pragma unroll
  for (int i = 0; i < MI; ++i)
#pragma unroll
    for (int j = 0; j < 4; ++j) acc[i][j] = (f4v){0.f, 0.f, 0.f, 0.f};

#pragma unroll
  for (int t = 0; t < MT / 64; ++t)
    cp16(&Ag[(size_t)(t * 64 + r0) * 1024 + csrc], &smem[0][(t * 256 + wave * 64) * 8]);
#pragma unroll
  for (int t = 0; t < 2; ++t)
    cp16(&Bg[(size_t)(t * 64 + r0) * 1024 + csrc], &smem[0][MT * 32 + (t * 256 + wave * 64) * 8]);

  for (int it = 0; it < 32; ++it) {
    __syncthreads();                       // drains stage(it) (issued last iter)
    if (it < 31) {
      int ko = (it + 1) * 32;
      int bi = (it + 1) & 1;
#pragma unroll
      for (int t = 0; t < MT / 64; ++t)
        cp16(&Ag[(size_t)(t * 64 + r0) * 1024 + ko + csrc], &smem[bi][(t * 256 + wave * 64) * 8]);
#pragma unroll
      for (int t = 0; t < 2; ++t)
        cp16(&Bg[(size_t)(t * 64 + r0) * 1024 + ko + csrc],
             &smem[bi][MT * 32 + (t * 256 + wave * 64) * 8]);
    }
    const u16* as = &smem[it & 1][0];
    const u16* bs = &smem[it & 1][MT * 32];
    bf8v af[MI], bfr[4];
#pragma unroll
    for (int i = 0; i < MI; ++i) af[i]  = *(const bf8v*)&as[(wr + i * 16 + ln) * 32 + co];
#pragma unroll
    for (int j = 0; j < 4; ++j) bfr[j] = *(const bf8v*)&bs[(wc + j * 16 + ln) * 32 + co];
#pragma unroll
    for (int i = 0; i < MI; ++i)
#pragma unroll
      for (int j = 0; j < 4; ++j)
        acc[i][j] = __builtin_amdgcn_mfma_f32_16x16x32_bf16(af[i], bfr[j], acc[i][j], 0, 0, 0);
  }

  if (mode == 2 || mode == 3) {
    // ---- LDS-bounce epilogue: T[token_local][feat_local] 128x128 bf16 ----
    if constexpr (MT == 128) {
      __syncthreads();                     // all waves done reading smem
      u16* T = &smem[0][0];                // 16384 u16 = 32KB, exact fit
      float bvs[4];
#pragma unroll
      for (int j = 0; j < 4; ++j) {
        int col = n0 + wc + j * 16 + ln;
        bvs[j] = bias_bf ? bf2f(((const u16*)bias)[col]) : ((const float*)bias)[col];
      }
#pragma unroll
      for (int i = 0; i < MI; ++i)
#pragma unroll
        for (int j = 0; j < 4; ++j)
#pragma unroll
          for (int r = 0; r < 4; ++r)
            T[(wr + i * 16 + qd * 4 + r) * 128 + (wc + j * 16 + ln)] =
                f2bf((acc[i][j][r] + bvs[j]) * cscale);
      __syncthreads();
      const int b_ = m0 >> 11, nl0 = m0 & 2047;
      const int tg0 = nl0 >> 6, h0 = n0 >> 6;
      u16* outp = (u16*)Cout;
#pragma unroll
      for (int pass = 0; pass < 8; ++pass) {
        int u = pass * 256 + tid;          // 2048 units of 16B
        int c2 = u >> 9, w = u & 511;
        int f = w >> 6, l = w & 63;
        int tt = c2 >> 1, hh = c2 & 1;     // token-tile half, head half
        u16* dstp = outp + (size_t)(b_ * 16 + h0 + hh) * 131072
                  + (size_t)(tg0 + tt) * 4096 + f * 512 + l * 8;
        if (mode == 3) {
          // kF: frag f=(ct*2+half), lane l=(qdk*16+lnk), jj = 8 consec feats
          int ct = f >> 1, half = f & 1, qdk = l >> 4, lnk = l & 15;
          int tok = tt * 64 + ct * 16 + lnk;
          int feat = hh * 64 + half * 32 + qdk * 8;
          *(bf8v*)dstp = *(const bf8v*)&T[tok * 128 + feat];
        } else {
          // vF: frag f=(c*4+dt), lane l=(qdf*16+lnf), jj=(g*4+r) token slots
          int c = f >> 2, dt = f & 3, qdf = l >> 4, lnf = l & 15;
          int featl = hh * 64 + dt * 16 + lnf;
          u16 vals[8];
#pragma unroll
          for (int jj = 0; jj < 8; ++jj) {
            int tokl = tt * 64 + c * 32 + (jj >> 2) * 16 + qdf * 4 + (jj & 3);
            vals[jj] = T[tokl * 128 + featl];
          }
          bf8v vv; __builtin_memcpy(&vv, vals, 16);
          *(bf8v*)dstp = vv;
        }
      }
    }
    return;
  }

  // ---- row-major epilogue (modes 0/1): C row = m0+wr+i*16+qd*4+r ----
#pragma unroll
  for (int j = 0; j < 4; ++j) {
    int col = n0 + wc + j * 16 + ln;
    float bv = bias_bf ? bf2f(((const u16*)bias)[col]) : ((const float*)bias)[col];
#pragma unroll
    for (int i = 0; i < MI; ++i) {
      int row = m0 + wr + i * 16 + qd * 4;
#pragma unroll
      for (int r = 0; r < 4; ++r) {
        float v = (acc[i][j][r] + bv) * cscale;
        if (mode == 1) ((u16*)Cout)[(size_t)(row + r) * 1024 + col] = f2bf(v);
        else           ((float*)Cout)[(size_t)(row + r) * 1024 + col] = v;
      }
    }
  }
}

// 1D grid 768, XCD-chunk swizzled: HW XCD = id%8. XCD k owns y-chunk (k>>1)
// (8 m-tiles) x x-chunk (k&1) (4 n-tiles) x all z. Within-XCD order: x
// innermost, then z, then y -> 12 consecutive blocks share one A panel.
__global__ __launch_bounds__(256) void k_gemm_qkv(const u16* xb, const u16* wt,
    const void* bq, const void* bk, const void* bv, const int* flags,
    u16* qpre, u16* kb, u16* vtb) {
  const int id = blockIdx.x;
  const int xcd = id & 7, j = id >> 3;    // j in [0,96)
  const int xw = j & 3, jj = j >> 2;      // jj in [0,24)
  const int z = jj % 3, yw = jj / 3;      // yw in [0,8)
  const int y = (xcd >> 1) * 8 + yw;      // m-tile in [0,32)
  const int x = (xcd & 1) * 4 + xw;       // n-tile in [0,8)
  const u16* Bt = wt + (size_t)z * (1u << 20);
  const void* bias = (z == 0) ? bq : (z == 1) ? bk : bv;
  if (z == 0)      gemm_bt<128>(xb, Bt, bias, flags[2], qpre, 1, 1.0f,   y * 128, x * 128);
  else if (z == 1) gemm_bt<128>(xb, Bt, bias, flags[4], kb,   3, KSCALE, y * 128, x * 128);
  else             gemm_bt<128>(xb, Bt, bias, flags[6], vtb,  2, 1.0f,   y * 128, x * 128);
}

// 1D grid 512, same swizzle idea: XCD k owns y-chunk (k>>1) (16 m-tiles of
// 64) x x-chunk (k&1) (4 n-tiles).
__global__ __launch_bounds__(256) void k_gemm_out(const u16* A, const u16* Bt,
    const void* bias, const int* flags, void* out) {
  const int id = blockIdx.x;
  const int xcd = id & 7, j = id >> 3;    // j in [0,64)
  const int xw = j & 3, yw = j >> 2;      // yw in [0,16)
  const int y = (xcd >> 1) * 16 + yw;     // m-tile in [0,64)
  const int x = (xcd & 1) * 4 + xw;       // n-tile in [0,8)
  gemm_bt<64>(A, Bt, bias, flags[8], out, flags[0] ? 1 : 0, 1.0f, y * 64, x * 128);
}

// ---------------------------------------------------------------------------
// LayerNorm over rows of 1024: block per row, 256 threads x 4 elems.
// (Separate-kernel form: fusing LN into attention cost ~10us — R21/R22.)
// ---------------------------------------------------------------------------
__global__ __launch_bounds__(256) void k_layernorm(const u16* __restrict__ qp,
    const void* __restrict__ g, const void* __restrict__ bb, const int* flags,
    u16* __restrict__ out) {
  int row = blockIdx.x, t = threadIdx.x;
  const u16* rp = qp + (size_t)row * 1024;
  ushort4 u = *(const ushort4*)(rp + t * 4);
  float x0 = bf2f(u.x), x1 = bf2f(u.y), x2 = bf2f(u.z), x3 = bf2f(u.w);
  float s = x0 + x1 + x2 + x3;
  float s2 = x0 * x0 + x1 * x1 + x2 * x2 + x3 * x3;
  for (int off = 32; off; off >>= 1) { s += __shfl_down(s, off); s2 += __shfl_down(s2, off); }
  __shared__ float red[10];
  int wave = t >> 6, lane = t & 63;
  if (lane == 0) { red[wave] = s; red[4 + wave] = s2; }
  __syncthreads();
  if (t == 0) {
    float S = red[0] + red[1] + red[2] + red[3];
    float S2 = red[4] + red[5] + red[6] + red[7];
    float mu = S * (1.f / 1024.f);
    float var = S2 * (1.f / 1024.f) - mu * mu;
    red[8] = mu; red[9] = rsqrtf(var + 1e-5f);
  }
  __syncthreads();
  float mu = red[8], rstd = red[9];
  int gf = flags[9], bf = flags[10];
  int c = t * 4;
  float gv[4], bv[4];
#pragma unroll
  for (int k = 0; k < 4; ++k) {
    gv[k] = gf ? bf2f(((const u16*)g)[c + k]) : ((const float*)g)[c + k];
    bv[k] = bf ? bf2f(((const u16*)bb)[c + k]) : ((const float*)bb)[c + k];
  }
  ushort4 o;
  o.x = f2bf((x0 - mu) * rstd * gv[0] + bv[0]);
  o.y = f2bf((x1 - mu) * rstd * gv[1] + bv[1]);
  o.z = f2bf((x2 - mu) * rstd * gv[2] + bv[2]);
  o.w = f2bf((x3 - mu) * rstd * gv[3] + bv[3]);
  *(ushort4*)(out + (size_t)row * 1024 + c) = o;
}

// ---------------------------------------------------------------------------
// One-tile attention compute from LDS-resident fragments (all static idx).
// ---------------------------------------------------------------------------
template <int NQS>
__device__ __forceinline__ void attn_tile(const bf8v kf[4][2], const bf8v vf[8],
    const bf8v qf[NQS][2], float ls[NQS][4], f4v o[NQS][4]) {
#pragma unroll
  for (int qs = 0; qs < NQS; ++qs) {
    unsigned pk[4][2];
#pragma unroll
    for (int ct = 0; ct < 4; ++ct) {
      f4v z = (f4v){0.f, 0.f, 0.f, 0.f};
      z = __builtin_amdgcn_mfma_f32_16x16x32_bf16(kf[ct][0], qf[qs][0], z, 0, 0, 0);  // S^T
      z = __builtin_amdgcn_mfma_f32_16x16x32_bf16(kf[ct][1], qf[qs][1], z, 0, 0, 0);
      float p0 = __builtin_amdgcn_exp2f(z[0]);
      float p1 = __builtin_amdgcn_exp2f(z[1]);
      float p2 = __builtin_amdgcn_exp2f(z[2]);
      float p3 = __builtin_amdgcn_exp2f(z[3]);
      ls[qs][0] += p0; ls[qs][1] += p1; ls[qs][2] += p2; ls[qs][3] += p3;
      pk[ct][0] = pack2bf(p0, p1);
      pk[ct][1] = pack2bf(p2, p3);
    }
#pragma unroll
    for (int c = 0; c < 2; ++c) {
      unsigned avals[4] = {pk[2*c][0], pk[2*c][1], pk[2*c+1][0], pk[2*c+1][1]};
      bf8v af; __builtin_memcpy(&af, avals, 16);
#pragma unroll
      for (int dt = 0; dt < 4; ++dt)
        o[qs][dt] = __builtin_amdgcn_mfma_f32_16x16x32_bf16(af, vf[c * 4 + dt], o[qs][dt], 0, 0, 0);
    }
  }
}

// ---------------------------------------------------------------------------
// Flash attention (R24 form, at its measured floor ~46.7us): 256-thread
// blocks (4 waves), each wave 32 q-rows. KVBLK=128: two 64-key tiles staged
// per barrier (16 barriers); LDS 64KB/block, 2 blocks/CU. setprio(1) wraps
// tile-compute. Grid 512 = XCD slot x 4 bh x 16 q-chunks; residual fused.
// ---------------------------------------------------------------------------
__global__ __launch_bounds__(256) void k_attention(const u16* __restrict__ qln,
    const u16* __restrict__ kfg, const u16* __restrict__ vfg, u16* __restrict__ attn) {
  const int x = blockIdx.x;
  const int xcd = x & 7, sl = x >> 3;                // sl in [0,64)
  const int bh = xcd * 4 + (sl >> 4), qc = sl & 15;  // 4 bh per XCD slot, 16 q-chunks
  const int b = bh >> 4, h = bh & 15;
  const int tid = threadIdx.x, wave = tid >> 6, lane = tid & 63;
  const int qd = lane >> 4, ln = lane & 15;
  const int qrow0 = qc * 128 + wave * 32;            // this wave's 32 q-rows

  const u16* kgb = kfg + (size_t)bh * 131072;        // kF fragment-ordered
  const u16* vgb = vfg + (size_t)bh * 131072;        // vF fragment-ordered

  __shared__ __align__(16) u16 kv[2][16384];         // [buf][K-pair 8192 | V-pair 8192]

  bf8v qf[2][2];
#pragma unroll
  for (int qs = 0; qs < 2; ++qs) {
    const u16* qb = qln + ((size_t)b * 2048 + qrow0 + qs * 16 + ln) * 1024 + h * 64;
    qf[qs][0] = *(const bf8v*)(qb + qd * 8);
    qf[qs][1] = *(const bf8v*)(qb + 32 + qd * 8);
  }
  float ls[2][4];
  f4v o[2][4];
#pragma unroll
  for (int qs = 0; qs < 2; ++qs)
#pragma unroll
    for (int r = 0; r < 4; ++r) { ls[qs][r] = 0.f; o[qs][r] = (f4v){0.f, 0.f, 0.f, 0.f}; }

  // prologue: stage tile-pair 0 (tiles 0,1) into buf 0: 8 cp16/thread = 32KB
#pragma unroll
  for (int q = 0; q < 4; ++q) {
    cp16(kgb + (size_t)(q * 256 + tid) * 8, &kv[0][(q * 256 + wave * 64) * 8]);
    cp16(vgb + (size_t)(q * 256 + tid) * 8, &kv[0][8192 + (q * 256 + wave * 64) * 8]);
  }

  for (int tp = 0; tp < 16; ++tp) {
    __syncthreads();                                 // drains stage(tp)
    if (tp < 15) {
      const u16* ks = kgb + (size_t)(tp + 1) * 8192;
      const u16* vs = vgb + (size_t)(tp + 1) * 8192;
      u16* dst = kv[(tp + 1) & 1];
#pragma unroll
      for (int q = 0; q < 4; ++q) {
        cp16(ks + (size_t)(q * 256 + tid) * 8, &dst[(q * 256 + wave * 64) * 8]);
        cp16(vs + (size_t)(q * 256 + tid) * 8, &dst[8192 + (q * 256 + wave * 64) * 8]);
      }
    }
    const u16* kvb = kv[tp & 1];
#pragma unroll
    for (int s = 0; s < 2; ++s) {                    // two 64-key tiles per pair
      const u16* kp = kvb + s * 4096;
      const u16* vp = kvb + 8192 + s * 4096;
      bf8v kfr[4][2], vfr[8];
#pragma unroll
      for (int ct = 0; ct < 4; ++ct) {
        kfr[ct][0] = *(const bf8v*)&kp[(ct * 2 + 0) * 512 + lane * 8];
        kfr[ct][1] = *(const bf8v*)&kp[(ct * 2 + 1) * 512 + lane * 8];
      }
#pragma unroll
      for (int cd = 0; cd < 8; ++cd)
        vfr[cd] = *(const bf8v*)&vp[cd * 512 + lane * 8];
      __builtin_amdgcn_s_setprio(1);
      attn_tile<2>(kfr, vfr, qf, ls, o);
      __builtin_amdgcn_s_setprio(0);
    }
  }

  // per q-subtile: reduce den (2 shuffles), store with fused residual
#pragma unroll
  for (int qs = 0; qs < 2; ++qs) {
    float lsum = (ls[qs][0] + ls[qs][1]) + (ls[qs][2] + ls[qs][3]);
    lsum += __shfl_xor(lsum, 16);
    lsum += __shfl_xor(lsum, 32);                     // den[q=ln] on every lane
    float rden[4];
#pragma unroll
    for (int r = 0; r < 4; ++r) {
      float dv = __shfl(lsum, (lane & 48) + qd * 4 + r);  // lane with ln=qd*4+r
      rden[r] = __builtin_amdgcn_rcpf(1e-8f + dv);
    }
#pragma unroll
    for (int dt = 0; dt < 4; ++dt) {
#pragma unroll
      for (int r = 0; r < 4; ++r) {
        size_t idx = ((size_t)b * 2048 + qrow0 + qs * 16 + qd * 4 + r) * 1024
                   + h * 64 + dt * 16 + ln;
        float val = o[qs][dt][r] * rden[r] + bf2f(qln[idx]);
        attn[idx] = f2bf(val);
      }
    }
  }
}

// ---------------------------------------------------------------------------
extern "C" void kernel_launch(void* const* d_in, const int* in_sizes, int n_in,
                              void* d_out, int out_size, void* d_ws, size_t ws_size,
                              hipStream_t stream) {
  // inputs: 0:x 1:Wq 2:bq 3:Wk 4:bk 5:Wv 6:bv 7:Wo 8:bo 9:ln_g 10:ln_b
  int* flags = (int*)d_ws;
  u16* base = (u16*)((char*)d_ws + 256);
  const size_t M1 = 1u << 20;
  u16* xb   = base;            // x bf16; overwritten by qln after gemm_qkv
  u16* wt   = base + 4 * M1;   // Wq^T,Wk^T,Wv^T,Wo^T (4 x 1M)
  u16* qpre = base + 8 * M1;   // q pre-LN; reused as attn-out after LN
  u16* kb   = base + 12 * M1;  // kF fragment-ordered K (pre-scaled by KSCALE)
  u16* vtb  = base + 16 * M1;  // vF fragment-ordered V (written by V-GEMM)
  u16* qln = xb;
  u16* at  = qpre;

  k_preprocess<<<3073, 256, 0, stream>>>(
      (const u16*)d_in[0], (const u16*)d_in[1], (const u16*)d_in[2], (const u16*)d_in[3],
      (const u16*)d_in[4], (const u16*)d_in[5], (const u16*)d_in[6], (const u16*)d_in[7],
      (const u16*)d_in[8], (const u16*)d_in[9], (const u16*)d_in[10], xb, wt, flags);
  k_gemm_qkv<<<768, 256, 0, stream>>>(xb, wt, d_in[2], d_in[4], d_in[6], flags,
                                      qpre, kb, vtb);
  k_layernorm<<<4096, 256, 0, stream>>>(qpre, d_in[9], d_in[10], flags, qln);
  k_attention<<<512, 256, 0, stream>>>(qln, kb, vtb, at);
  k_gemm_out<<<512, 256, 0, stream>>>(at, wt + 3 * M1, d_in[8], flags, d_out);
}

// Round 16
// 205.970 us; speedup vs baseline: 1.0299x; 1.0161x over previous
//
#include <hip/hip_runtime.h>

// ============================================================================
// EfficientAttention: x->(QKV proj)->LN(q)->flash attention->(+q)->out proj
// B=2, N=2048, D=1024, H=16, d=64.  bf16 MFMA pipeline, fp32 accumulate.
// R28 = R27 with the barrier race FIXED: R27's fused "s_waitcnt vmcnt(N);
//      s_barrier" omitted lgkmcnt(0), so a wave could cross the barrier with
//      its last ds_reads of buf[(it-1)%3] still in flight while another wave
//      began cp16-overwriting that buffer (absmax 0.23). __syncthreads()
//      always drains lgkmcnt before s_barrier; the counted-vmcnt version
//      must too: "s_waitcnt vmcnt(N) lgkmcnt(0); s_barrier". lgkmcnt(0) is
//      ~free (compiler already waited those reads for the MFMAs).
// R27: GEMM K-loop with T4 counted-vmcnt + stage distance 2 (triple-buffered
//      LDS): stage(t+2) issues after barrier(t); loop-top waits only for the
//      stage about to be read (vmcnt(4) qkv / vmcnt(3) out); newest stage's
//      loads stay in flight ACROSS the barrier -> each stage gets 2 compute
//      phases to land (m218: counted vs drain0 = +38-73%). LDS 48KB/36KB.
//      Epilogues (R25 coalesced kF/vF bounce) drain via __syncthreads.
//      Attention frozen at R24 floor (47us); LN separate; swizzles as R21.
// ============================================================================

typedef unsigned short u16;
typedef __attribute__((ext_vector_type(8))) short bf8v;   // 8 bf16 (bit-pattern shorts)
typedef __attribute__((ext_vector_type(4))) float f4v;    // MFMA acc

typedef __attribute__((address_space(1))) void gvoid;
typedef __attribute__((address_space(3))) void lvoid;
__device__ __forceinline__ void cp16(const void* g, void* l) {
  __builtin_amdgcn_global_load_lds((gvoid*)g, (lvoid*)l, 16, 0, 0);
}

__device__ __forceinline__ float bf2f(u16 u) {
  unsigned int x = ((unsigned int)u) << 16;
  float f; __builtin_memcpy(&f, &x, 4); return f;
}
__device__ __forceinline__ u16 f2bf(float f) {
  unsigned int x; __builtin_memcpy(&x, &f, 4);
  unsigned int r = (x + 0x7fffu + ((x >> 16) & 1u)) >> 16;   // RNE
  return (u16)r;
}
// pack 2 floats' bf16 truncations into one u32 (a -> low16, b -> high16)
__device__ __forceinline__ unsigned pack2bf(float a, float b) {
  unsigned ua, ub;
  __builtin_memcpy(&ua, &a, 4); __builtin_memcpy(&ub, &b, 4);
  return __builtin_amdgcn_perm(ub, ua, 0x07060302u);
}

#define KSCALE 0.18033688011f   // log2(e) / sqrt(64)

// ---------------------------------------------------------------------------
// Fused preprocessing: ONE launch does
//   blocks [0,2048):      x -> bf16 copy (self-classified)
//   blocks [2048,3072):   W0..W3 transpose to wt (self-classified)
//   block  3072:          the 11-tensor flags classifier
// ---------------------------------------------------------------------------
__global__ __launch_bounds__(256) void k_preprocess(
    const u16* a0, const u16* a1, const u16* a2, const u16* a3,
    const u16* a4, const u16* a5, const u16* a6, const u16* a7,
    const u16* a8, const u16* a9, const u16* a10,
    u16* xb, u16* wt, int* flags) {
  const int blk = blockIdx.x;
  const int t = threadIdx.x;
  __shared__ u16 tile[64 * 65];
  __shared__ int cls[3];

  if (blk >= 3072) {
    // ---- flags classifier ----
    if (t >= 11) return;
    const u16* arr[11] = {a0,a1,a2,a3,a4,a5,a6,a7,a8,a9,a10};
    const u16* p = arr[t];
    int ze = 0, no = 0, pe = 0;
    for (int i = 0; i < 128; ++i) {
      u16 he = p[2*i], ho = p[2*i+1];
      if (he == 0) ze++;
      if (ho != 0) no++;
      int e = (he >> 7) & 0xff;
      if (he == 0 || (e >= 64 && e <= 160)) pe++;
    }
    int isbf;
    if (ze >= 100 && no >= 64) isbf = 0;
    else isbf = (pe >= 100) ? 1 : 0;
    flags[t] = isbf;
    return;
  }

  // ---- self-classification of this block's source tensor ----
  int wz = (blk - 2048) >> 8;                       // W index (transpose blocks)
  const u16* src = (blk < 2048) ? a0
                 : (wz == 0) ? a1 : (wz == 1) ? a3 : (wz == 2) ? a5 : a7;
  if (t == 0) { cls[0] = 0; cls[1] = 0; cls[2] = 0; }
  __syncthreads();
  if (t < 128) {
    u16 he = src[2*t], ho = src[2*t+1];
    int e = (he >> 7) & 0xff;
    if (he == 0) atomicAdd(&cls[0], 1);
    if (ho != 0) atomicAdd(&cls[1], 1);
    if (he == 0 || (e >= 64 && e <= 160)) atomicAdd(&cls[2], 1);
  }
  __syncthreads();
  int isbf;
  if (cls[0] >= 100 && cls[1] >= 64) isbf = 0;
  else isbf = (cls[2] >= 100) ? 1 : 0;

  if (blk < 2048) {
    // ---- convert x -> bf16 (8 elems/thread) ----
    size_t i = ((size_t)blk * 256 + t) * 8;
    if (isbf) {
      *(float4*)(xb + i) = *((const float4*)(a0 + i));
    } else {
      const float* xf = (const float*)a0;
      float4 a = *(const float4*)(xf + i);
      float4 b = *(const float4*)(xf + i + 4);
      ushort4 o0, o1;
      o0.x = f2bf(a.x); o0.y = f2bf(a.y); o0.z = f2bf(a.z); o0.w = f2bf(a.w);
      o1.x = f2bf(b.x); o1.y = f2bf(b.y); o1.z = f2bf(b.z); o1.w = f2bf(b.w);
      *(ushort4*)(xb + i) = o0; *(ushort4*)(xb + i + 4) = o1;
    }
    return;
  }

  // ---- transpose W[wz]: 64x64 tile (pad 65 => 2-way banks) ----
  {
    int rem = (blk - 2048) & 255;
    int r0 = ((rem >> 4) & 15) * 64, c0 = (rem & 15) * 64;
    u16* dst = wt + (size_t)wz * (1u << 20);
    for (int rr = 0; rr < 2; ++rr) {
      int row = rr * 32 + (t >> 3);
      int c8 = (t & 7) * 8;
      u16 v[8];
      if (isbf) {
        const u16* Ws = src;
        ushort4 a = *(const ushort4*)&Ws[(size_t)(r0 + row) * 1024 + c0 + c8];
        ushort4 b = *(const ushort4*)&Ws[(size_t)(r0 + row) * 1024 + c0 + c8 + 4];
        v[0]=a.x; v[1]=a.y; v[2]=a.z; v[3]=a.w; v[4]=b.x; v[5]=b.y; v[6]=b.z; v[7]=b.w;
      } else {
        const float* Wf = (const float*)src;
        float4 a = *(const float4*)&Wf[(size_t)(r0 + row) * 1024 + c0 + c8];
        float4 b = *(const float4*)&Wf[(size_t)(r0 + row) * 1024 + c0 + c8 + 4];
        v[0]=f2bf(a.x); v[1]=f2bf(a.y); v[2]=f2bf(a.z); v[3]=f2bf(a.w);
        v[4]=f2bf(b.x); v[5]=f2bf(b.y); v[6]=f2bf(b.z); v[7]=f2bf(b.w);
      }
#pragma unroll
      for (int j = 0; j < 8; ++j) tile[row * 65 + c8 + j] = v[j];
    }
    __syncthreads();
    for (int rr = 0; rr < 2; ++rr) {
      int nrow = rr * 32 + (t >> 3);
      int k8 = (t & 7) * 8;
      u16 v[8];
#pragma unroll
      for (int j = 0; j < 8; ++j) v[j] = tile[(k8 + j) * 65 + nrow];
      ushort4 o0, o1;
      o0.x=v[0]; o0.y=v[1]; o0.z=v[2]; o0.w=v[3];
      o1.x=v[4]; o1.y=v[5]; o1.z=v[6]; o1.w=v[7];
      *(ushort4*)&dst[(size_t)(c0 + nrow) * 1024 + r0 + k8] = o0;
      *(ushort4*)&dst[(size_t)(c0 + nrow) * 1024 + r0 + k8 + 4] = o1;
    }
  }
}

// ---------------------------------------------------------------------------
// MTx128-tile gemm_bt: C[m0..m0+MT, n0..n0+128] = A @ Bt^T + bias
// BK=32, TRIPLE-buffered LDS, stage distance 2, counted vmcnt (T4):
// loop-top "s_waitcnt vmcnt(NLOADS) lgkmcnt(0)" + s_barrier in one asm
// (memory clobber). vmcnt(N): only the stage about to be read must have
// landed. lgkmcnt(0): this wave's ds_reads of the buffer the NEXT stage
// will overwrite are complete before crossing the barrier (the R27 race).
// mode: 0 = fp32 rowmajor, 1 = bf16 rowmajor,
//       2 = bf16 -> vF via LDS-bounce, 3 = bf16 -> kF via LDS-bounce
// Modes 2/3 require MT == 128 (bounce tile T = smem[0..1], 32KB).
// ---------------------------------------------------------------------------
template <int MT>
__device__ __forceinline__ void gemm_bt(const u16* __restrict__ A, const u16* __restrict__ Bt,
    const void* __restrict__ bias, int bias_bf, void* __restrict__ Cout, int mode,
    float cscale, int m0, int n0) {
  constexpr int MI = MT / 32;                             // acc row-tiles per wave
  constexpr int BUFE = (MT + 128) * 32;                   // u16 per buffer
  __shared__ __align__(16) u16 smem[3][BUFE];             // [buf][As MT*32 | Bs 128*32]
  const int tid = threadIdx.x;
  const int wave = tid >> 6, lane = tid & 63;
  const int qd = lane >> 4, ln = lane & 15;
  const int wr = (wave >> 1) * (MT / 2), wc = (wave & 1) * 64;
  const int r0 = wave * 16 + (lane >> 2);
  const int csrc = ((lane & 3) ^ ((lane >> 2) & 3)) * 8;  // swizzled src chunk
  const u16* Ag = &A[(size_t)m0 * 1024];
  const u16* Bg = &Bt[(size_t)n0 * 1024];
  const int co = (qd ^ (ln & 3)) * 8;                     // frag-read chunk
  f4v acc[MI][4];
#pragma unroll
  for (int i = 0; i < MI; ++i)
#pragma unroll
    for (int j = 0; j < 4; ++j) acc[i][j] = (f4v){0.f, 0.f, 0.f, 0.f};

  // stage K-tile kt into buffer bi (NLOADS cp16 per thread)
  auto stage = [&](int kt, int bi) {
    int ko = kt * 32;
#pragma unroll
    for (int t = 0; t < MT / 64; ++t)
      cp16(&Ag[(size_t)(t * 64 + r0) * 1024 + ko + csrc], &smem[bi][(t * 256 + wave * 64) * 8]);
#pragma unroll
    for (int t = 0; t < 2; ++t)
      cp16(&Bg[(size_t)(t * 64 + r0) * 1024 + ko + csrc],
           &smem[bi][MT * 32 + (t * 256 + wave * 64) * 8]);
  };

  // prologue: stages 0 and 1 in flight (2*NLOADS outstanding)
  stage(0, 0);
  stage(1, 1);

  for (int it = 0; it < 32; ++it) {
    // wait for stage(it) + this wave's ds_reads, then sync. Newest stage's
    // loads stay in flight across the barrier.
    if (it < 31) {
      if constexpr (MT == 128)
        asm volatile("s_waitcnt vmcnt(4) lgkmcnt(0)\n\ts_barrier" ::: "memory");
      else
        asm volatile("s_waitcnt vmcnt(3) lgkmcnt(0)\n\ts_barrier" ::: "memory");
    } else {
      asm volatile("s_waitcnt vmcnt(0) lgkmcnt(0)\n\ts_barrier" ::: "memory");
    }
    if (it + 2 < 32) stage(it + 2, (it + 2) % 3);
    const u16* as = &smem[it % 3][0];
    const u16* bs = &smem[it % 3][MT * 32];
    bf8v af[MI], bfr[4];
#pragma unroll
    for (int i = 0; i < MI; ++i) af[i]  = *(const bf8v*)&as[(wr + i * 16 + ln) * 32 + co];
#pragma unroll
    for (int j = 0; j < 4; ++j) bfr[j] = *(const bf8v*)&bs[(wc + j * 16 + ln) * 32 + co];
#pragma unroll
    for (int i = 0; i < MI; ++i)
#pragma unroll
      for (int j = 0; j < 4; ++j)
        acc[i][j] = __builtin_amdgcn_mfma_f32_16x16x32_bf16(af[i], bfr[j], acc[i][j], 0, 0, 0);
  }

  if (mode == 2 || mode == 3) {
    // ---- LDS-bounce epilogue: T[token_local][feat_local] 128x128 bf16 ----
    if constexpr (MT == 128) {
      __syncthreads();                     // drain + all waves done with smem
      u16* T = &smem[0][0];                // 16384 u16 = 32KB (bufs 0+1)
      float bvs[4];
#pragma unroll
      for (int j = 0; j < 4; ++j) {
        int col = n0 + wc + j * 16 + ln;
        bvs[j] = bias_bf ? bf2f(((const u16*)bias)[col]) : ((const float*)bias)[col];
      }
#pragma unroll
      for (int i = 0; i < MI; ++i)
#pragma unroll
        for (int j = 0; j < 4; ++j)
#pragma unroll
          for (int r = 0; r < 4; ++r)
            T[(wr + i * 16 + qd * 4 + r) * 128 + (wc + j * 16 + ln)] =
                f2bf((acc[i][j][r] + bvs[j]) * cscale);
      __syncthreads();
      const int b_ = m0 >> 11, nl0 = m0 & 2047;
      const int tg0 = nl0 >> 6, h0 = n0 >> 6;
      u16* outp = (u16*)Cout;
#pragma unroll
      for (int pass = 0; pass < 8; ++pass) {
        int u = pass * 256 + tid;          // 2048 units of 16B
        int c2 = u >> 9, w = u & 511;
        int f = w >> 6, l = w & 63;
        int tt = c2 >> 1, hh = c2 & 1;     // token-tile half, head half
        u16* dstp = outp + (size_t)(b_ * 16 + h0 + hh) * 131072
                  + (size_t)(tg0 + tt) * 4096 + f * 512 + l * 8;
        if (mode == 3) {
          // kF: frag f=(ct*2+half), lane l=(qdk*16+lnk), jj = 8 consec feats
          int ct = f >> 1, half = f & 1, qdk = l >> 4, lnk = l & 15;
          int tok = tt * 64 + ct * 16 + lnk;
          int feat = hh * 64 + half * 32 + qdk * 8;
          *(bf8v*)dstp = *(const bf8v*)&T[tok * 128 + feat];
        } else {
          // vF: frag f=(c*4+dt), lane l=(qdf*16+lnf), jj=(g*4+r) token slots
          int c = f >> 2, dt = f & 3, qdf = l >> 4, lnf = l & 15;
          int featl = hh * 64 + dt * 16 + lnf;
          u16 vals[8];
#pragma unroll
          for (int jj = 0; jj < 8; ++jj) {
            int tokl = tt * 64 + c * 32 + (jj >> 2) * 16 + qdf * 4 + (jj & 3);
            vals[jj] = T[tokl * 128 + featl];
          }
          bf8v vv; __builtin_memcpy(&vv, vals, 16);
          *(bf8v*)dstp = vv;
        }
      }
    }
    return;
  }

  // ---- row-major epilogue (modes 0/1): C row = m0+wr+i*16+qd*4+r ----
#pragma unroll
  for (int j = 0; j < 4; ++j) {
    int col = n0 + wc + j * 16 + ln;
    float bv = bias_bf ? bf2f(((const u16*)bias)[col]) : ((const float*)bias)[col];
#pragma unroll
    for (int i = 0; i < MI; ++i) {
      int row = m0 + wr + i * 16 + qd * 4;
#pragma unroll
      for (int r = 0; r < 4; ++r) {
        float v = (acc[i][j][r] + bv) * cscale;
        if (mode == 1) ((u16*)Cout)[(size_t)(row + r) * 1024 + col] = f2bf(v);
        else           ((float*)Cout)[(size_t)(row + r) * 1024 + col] = v;
      }
    }
  }
}

// 1D grid 768, XCD-chunk swizzled: HW XCD = id%8. XCD k owns y-chunk (k>>1)
// (8 m-tiles) x x-chunk (k&1) (4 n-tiles) x all z. Within-XCD order: x
// innermost, then z, then y -> 12 consecutive blocks share one A panel.
__global__ __launch_bounds__(256) void k_gemm_qkv(const u16* xb, const u16* wt,
    const void* bq, const void* bk, const void* bv, const int* flags,
    u16* qpre, u16* kb, u16* vtb) {
  const int id = blockIdx.x;
  const int xcd = id & 7, j = id >> 3;    // j in [0,96)
  const int xw = j & 3, jj = j >> 2;      // jj in [0,24)
  const int z = jj % 3, yw = jj / 3;      // yw in [0,8)
  const int y = (xcd >> 1) * 8 + yw;      // m-tile in [0,32)
  const int x = (xcd & 1) * 4 + xw;       // n-tile in [0,8)
  const u16* Bt = wt + (size_t)z * (1u << 20);
  const void* bias = (z == 0) ? bq : (z == 1) ? bk : bv;
  if (z == 0)      gemm_bt<128>(xb, Bt, bias, flags[2], qpre, 1, 1.0f,   y * 128, x * 128);
  else if (z == 1) gemm_bt<128>(xb, Bt, bias, flags[4], kb,   3, KSCALE, y * 128, x * 128);
  else             gemm_bt<128>(xb, Bt, bias, flags[6], vtb,  2, 1.0f,   y * 128, x * 128);
}

// 1D grid 512, same swizzle idea: XCD k owns y-chunk (k>>1) (16 m-tiles of
// 64) x x-chunk (k&1) (4 n-tiles).
__global__ __launch_bounds__(256) void k_gemm_out(const u16* A, const u16* Bt,
    const void* bias, const int* flags, void* out) {
  const int id = blockIdx.x;
  const int xcd = id & 7, j = id >> 3;    // j in [0,64)
  const int xw = j & 3, yw = j >> 2;      // yw in [0,16)
  const int y = (xcd >> 1) * 16 + yw;     // m-tile in [0,64)
  const int x = (xcd & 1) * 4 + xw;       // n-tile in [0,8)
  gemm_bt<64>(A, Bt, bias, flags[8], out, flags[0] ? 1 : 0, 1.0f, y * 64, x * 128);
}

// ---------------------------------------------------------------------------
// LayerNorm over rows of 1024: block per row, 256 threads x 4 elems.
// (Separate-kernel form: fusing LN into attention cost ~10us — R21/R22.)
// ---------------------------------------------------------------------------
__global__ __launch_bounds__(256) void k_layernorm(const u16* __restrict__ qp,
    const void* __restrict__ g, const void* __restrict__ bb, const int* flags,
    u16* __restrict__ out) {
  int row = blockIdx.x, t = threadIdx.x;
  const u16* rp = qp + (size_t)row * 1024;
  ushort4 u = *(const ushort4*)(rp + t * 4);
  float x0 = bf2f(u.x), x1 = bf2f(u.y), x2 = bf2f(u.z), x3 = bf2f(u.w);
  float s = x0 + x1 + x2 + x3;
  float s2 = x0 * x0 + x1 * x1 + x2 * x2 + x3 * x3;
  for (int off = 32; off; off >>= 1) { s += __shfl_down(s, off); s2 += __shfl_down(s2, off); }
  __shared__ float red[10];
  int wave = t >> 6, lane = t & 63;
  if (lane == 0) { red[wave] = s; red[4 + wave] = s2; }
  __syncthreads();
  if (t == 0) {
    float S = red[0] + red[1] + red[2] + red[3];
    float S2 = red[4] + red[5] + red[6] + red[7];
    float mu = S * (1.f / 1024.f);
    float var = S2 * (1.f / 1024.f) - mu * mu;
    red[8] = mu; red[9] = rsqrtf(var + 1e-5f);
  }
  __syncthreads();
  float mu = red[8], rstd = red[9];
  int gf = flags[9], bf = flags[10];
  int c = t * 4;
  float gv[4], bv[4];
#pragma unroll
  for (int k = 0; k < 4; ++k) {
    gv[k] = gf ? bf2f(((const u16*)g)[c + k]) : ((const float*)g)[c + k];
    bv[k] = bf ? bf2f(((const u16*)bb)[c + k]) : ((const float*)bb)[c + k];
  }
  ushort4 o;
  o.x = f2bf((x0 - mu) * rstd * gv[0] + bv[0]);
  o.y = f2bf((x1 - mu) * rstd * gv[1] + bv[1]);
  o.z = f2bf((x2 - mu) * rstd * gv[2] + bv[2]);
  o.w = f2bf((x3 - mu) * rstd * gv[3] + bv[3]);
  *(ushort4*)(out + (size_t)row * 1024 + c) = o;
}

// ---------------------------------------------------------------------------
// One-tile attention compute from LDS-resident fragments (all static idx).
// ---------------------------------------------------------------------------
template <int NQS>
__device__ __forceinline__ void attn_tile(const bf8v kf[4][2], const bf8v vf[8],
    const bf8v qf[NQS][2], float ls[NQS][4], f4v o[NQS][4]) {
#pragma unroll
  for (int qs = 0; qs < NQS; ++qs) {
    unsigned pk[4][2];
#pragma unroll
    for (int ct = 0; ct < 4; ++ct) {
      f4v z = (f4v){0.f, 0.f, 0.f, 0.f};
      z = __builtin_amdgcn_mfma_f32_16x16x32_bf16(kf[ct][0], qf[qs][0], z, 0, 0, 0);  // S^T
      z = __builtin_amdgcn_mfma_f32_16x16x32_bf16(kf[ct][1], qf[qs][1], z, 0, 0, 0);
      float p0 = __builtin_amdgcn_exp2f(z[0]);
      float p1 = __builtin_amdgcn_exp2f(z[1]);
      float p2 = __builtin_amdgcn_exp2f(z[2]);
      float p3 = __builtin_amdgcn_exp2f(z[3]);
      ls[qs][0] += p0; ls[qs][1] += p1; ls[qs][2] += p2; ls[qs][3] += p3;
      pk[ct][0] = pack2bf(p0, p1);
      pk[ct][1] = pack2bf(p2, p3);
    }
#pragma unroll
    for (int c = 0; c < 2; ++c) {
      unsigned avals[4] = {pk[2*c][0], pk[2*c][1], pk[2*c+1][0], pk[2*c+1][1]};
      bf8v af; __builtin_memcpy(&af, avals, 16);
#pragma unroll
      for (int dt = 0; dt < 4; ++dt)
        o[qs][dt] = __builtin_amdgcn_mfma_f32_16x16x32_bf16(af, vf[c * 4 + dt], o[qs][dt], 0, 0, 0);
    }
  }
}

// ---------------------------------------------------------------------------
// Flash attention (R24 form, measured floor ~47us): 256-thread blocks (4
// waves), each wave 32 q-rows. KVBLK=128: two 64-key tiles staged per
// barrier (16 barriers); LDS 64KB/block, 2 blocks/CU. setprio(1) wraps
// tile-compute. Grid 512 = XCD slot x 4 bh x 16 q-chunks; residual fused.
// ---------------------------------------------------------------------------
__global__ __launch_bounds__(256) void k_attention(const u16* __restrict__ qln,
    const u16* __restrict__ kfg, const u16* __restrict__ vfg, u16* __restrict__ attn) {
  const int x = blockIdx.x;
  const int xcd = x & 7, sl = x >> 3;                // sl in [0,64)
  const int bh = xcd * 4 + (sl >> 4), qc = sl & 15;  // 4 bh per XCD slot, 16 q-chunks
  const int b = bh >> 4, h = bh & 15;
  const int tid = threadIdx.x, wave = tid >> 6, lane = tid & 63;
  const int qd = lane >> 4, ln = lane & 15;
  const int qrow0 = qc * 128 + wave * 32;            // this wave's 32 q-rows

  const u16* kgb = kfg + (size_t)bh * 131072;        // kF fragment-ordered
  const u16* vgb = vfg + (size_t)bh * 131072;        // vF fragment-ordered

  __shared__ __align__(16) u16 kv[2][16384];         // [buf][K-pair 8192 | V-pair 8192]

  bf8v qf[2][2];
#pragma unroll
  for (int qs = 0; qs < 2; ++qs) {
    const u16* qb = qln + ((size_t)b * 2048 + qrow0 + qs * 16 + ln) * 1024 + h * 64;
    qf[qs][0] = *(const bf8v*)(qb + qd * 8);
    qf[qs][1] = *(const bf8v*)(qb + 32 + qd * 8);
  }
  float ls[2][4];
  f4v o[2][4];
#pragma unroll
  for (int qs = 0; qs < 2; ++qs)
#pragma unroll
    for (int r = 0; r < 4; ++r) { ls[qs][r] = 0.f; o[qs][r] = (f4v){0.f, 0.f, 0.f, 0.f}; }

  // prologue: stage tile-pair 0 (tiles 0,1) into buf 0: 8 cp16/thread = 32KB
#pragma unroll
  for (int q = 0; q < 4; ++q) {
    cp16(kgb + (size_t)(q * 256 + tid) * 8, &kv[0][(q * 256 + wave * 64) * 8]);
    cp16(vgb + (size_t)(q * 256 + tid) * 8, &kv[0][8192 + (q * 256 + wave * 64) * 8]);
  }

  for (int tp = 0; tp < 16; ++tp) {
    __syncthreads();                                 // drains stage(tp)
    if (tp < 15) {
      const u16* ks = kgb + (size_t)(tp + 1) * 8192;
      const u16* vs = vgb + (size_t)(tp + 1) * 8192;
      u16* dst = kv[(tp + 1) & 1];
#pragma unroll
      for (int q = 0; q < 4; ++q) {
        cp16(ks + (size_t)(q * 256 + tid) * 8, &dst[(q * 256 + wave * 64) * 8]);
        cp16(vs + (size_t)(q * 256 + tid) * 8, &dst[8192 + (q * 256 + wave * 64) * 8]);
      }
    }
    const u16* kvb = kv[tp & 1];
#pragma unroll
    for (int s = 0; s < 2; ++s) {                    // two 64-key tiles per pair
      const u16* kp = kvb + s * 4096;
      const u16* vp = kvb + 8192 + s * 4096;
      bf8v kfr[4][2], vfr[8];
#pragma unroll
      for (int ct = 0; ct < 4; ++ct) {
        kfr[ct][0] = *(const bf8v*)&kp[(ct * 2 + 0) * 512 + lane * 8];
        kfr[ct][1] = *(const bf8v*)&kp[(ct * 2 + 1) * 512 + lane * 8];
      }
#pragma unroll
      for (int cd = 0; cd < 8; ++cd)
        vfr[cd] = *(const bf8v*)&vp[cd * 512 + lane * 8];
      __builtin_amdgcn_s_setprio(1);
      attn_tile<2>(kfr, vfr, qf, ls, o);
      __builtin_amdgcn_s_setprio(0);
    }
  }

  // per q-subtile: reduce den (2 shuffles), store with fused residual
#pragma unroll
  for (int qs = 0; qs < 2; ++qs) {
    float lsum = (ls[qs][0] + ls[qs][1]) + (ls[qs][2] + ls[qs][3]);
    lsum += __shfl_xor(lsum, 16);
    lsum += __shfl_xor(lsum, 32);                     // den[q=ln] on every lane
    float rden[4];
#pragma unroll
    for (int r = 0; r < 4; ++r) {
      float dv = __shfl(lsum, (lane & 48) + qd * 4 + r);  // lane with ln=qd*4+r
      rden[r] = __builtin_amdgcn_rcpf(1e-8f + dv);
    }
#pragma unroll
    for (int dt = 0; dt < 4; ++dt) {
#pragma unroll
      for (int r = 0; r < 4; ++r) {
        size_t idx = ((size_t)b * 2048 + qrow0 + qs * 16 + qd * 4 + r) * 1024
                   + h * 64 + dt * 16 + ln;
        float val = o[qs][dt][r] * rden[r] + bf2f(qln[idx]);
        attn[idx] = f2bf(val);
      }
    }
  }
}

// ---------------------------------------------------------------------------
extern "C" void kernel_launch(void* const* d_in, const int* in_sizes, int n_in,
                              void* d_out, int out_size, void* d_ws, size_t ws_size,
                              hipStream_t stream) {
  // inputs: 0:x 1:Wq 2:bq 3:Wk 4:bk 5:Wv 6:bv 7:Wo 8:bo 9:ln_g 10:ln_b
  int* flags = (int*)d_ws;
  u16* base = (u16*)((char*)d_ws + 256);
  const size_t M1 = 1u << 20;
  u16* xb   = base;            // x bf16; overwritten by qln after gemm_qkv
  u16* wt   = base + 4 * M1;   // Wq^T,Wk^T,Wv^T,Wo^T (4 x 1M)
  u16* qpre = base + 8 * M1;   // q pre-LN; reused as attn-out after LN
  u16* kb   = base + 12 * M1;  // kF fragment-ordered K (pre-scaled by KSCALE)
  u16* vtb  = base + 16 * M1;  // vF fragment-ordered V (written by V-GEMM)
  u16* qln = xb;
  u16* at  = qpre;

  k_preprocess<<<3073, 256, 0, stream>>>(
      (const u16*)d_in[0], (const u16*)d_in[1], (const u16*)d_in[2], (const u16*)d_in[3],
      (const u16*)d_in[4], (const u16*)d_in[5], (const u16*)d_in[6], (const u16*)d_in[7],
      (const u16*)d_in[8], (const u16*)d_in[9], (const u16*)d_in[10], xb, wt, flags);
  k_gemm_qkv<<<768, 256, 0, stream>>>(xb, wt, d_in[2], d_in[4], d_in[6], flags,
                                      qpre, kb, vtb);
  k_layernorm<<<4096, 256, 0, stream>>>(qpre, d_in[9], d_in[10], flags, qln);
  k_attention<<<512, 256, 0, stream>>>(qln, kb, vtb, at);
  k_gemm_out<<<512, 256, 0, stream>>>(at, wt + 3 * M1, d_in[8], flags, d_out);
}

// Round 17
// 202.547 us; speedup vs baseline: 1.0473x; 1.0169x over previous
//
#include <hip/hip_runtime.h>

// ============================================================================
// EfficientAttention: x->(QKV proj)->LN(q)->flash attention->(+q)->out proj
// B=2, N=2048, D=1024, H=16, d=64.  bf16 MFMA pipeline, fp32 accumulate.
// R29: GEMM addressing strength-reduction on top of R28's T4 loop. R20's qkv
//      counters showed VALU:MFMA = 2:1 (31% vs 15.6%) -- address arithmetic,
//      not math. (a) invariant per-thread global stage pointers hoisted out
//      of the K-loop (stage adds only ko); (b) K-loop unrolled x3 so the
//      mod-3 buffer index is the compile-time unroll index: all smem[u]
//      ds_read/write addresses become static immediates. Barrier semantics
//      (counted vmcnt + lgkmcnt(0) -- the R28 fix), epilogues (R25 coalesced
//      bounce), swizzles, LN, attention (R24 floor, 46.5us) all unchanged.
// ============================================================================

typedef unsigned short u16;
typedef __attribute__((ext_vector_type(8))) short bf8v;   // 8 bf16 (bit-pattern shorts)
typedef __attribute__((ext_vector_type(4))) float f4v;    // MFMA acc

typedef __attribute__((address_space(1))) void gvoid;
typedef __attribute__((address_space(3))) void lvoid;
__device__ __forceinline__ void cp16(const void* g, void* l) {
  __builtin_amdgcn_global_load_lds((gvoid*)g, (lvoid*)l, 16, 0, 0);
}

__device__ __forceinline__ float bf2f(u16 u) {
  unsigned int x = ((unsigned int)u) << 16;
  float f; __builtin_memcpy(&f, &x, 4); return f;
}
__device__ __forceinline__ u16 f2bf(float f) {
  unsigned int x; __builtin_memcpy(&x, &f, 4);
  unsigned int r = (x + 0x7fffu + ((x >> 16) & 1u)) >> 16;   // RNE
  return (u16)r;
}
// pack 2 floats' bf16 truncations into one u32 (a -> low16, b -> high16)
__device__ __forceinline__ unsigned pack2bf(float a, float b) {
  unsigned ua, ub;
  __builtin_memcpy(&ua, &a, 4); __builtin_memcpy(&ub, &b, 4);
  return __builtin_amdgcn_perm(ub, ua, 0x07060302u);
}

#define KSCALE 0.18033688011f   // log2(e) / sqrt(64)

// ---------------------------------------------------------------------------
// Fused preprocessing: ONE launch does
//   blocks [0,2048):      x -> bf16 copy (self-classified)
//   blocks [2048,3072):   W0..W3 transpose to wt (self-classified)
//   block  3072:          the 11-tensor flags classifier
// ---------------------------------------------------------------------------
__global__ __launch_bounds__(256) void k_preprocess(
    const u16* a0, const u16* a1, const u16* a2, const u16* a3,
    const u16* a4, const u16* a5, const u16* a6, const u16* a7,
    const u16* a8, const u16* a9, const u16* a10,
    u16* xb, u16* wt, int* flags) {
  const int blk = blockIdx.x;
  const int t = threadIdx.x;
  __shared__ u16 tile[64 * 65];
  __shared__ int cls[3];

  if (blk >= 3072) {
    // ---- flags classifier ----
    if (t >= 11) return;
    const u16* arr[11] = {a0,a1,a2,a3,a4,a5,a6,a7,a8,a9,a10};
    const u16* p = arr[t];
    int ze = 0, no = 0, pe = 0;
    for (int i = 0; i < 128; ++i) {
      u16 he = p[2*i], ho = p[2*i+1];
      if (he == 0) ze++;
      if (ho != 0) no++;
      int e = (he >> 7) & 0xff;
      if (he == 0 || (e >= 64 && e <= 160)) pe++;
    }
    int isbf;
    if (ze >= 100 && no >= 64) isbf = 0;
    else isbf = (pe >= 100) ? 1 : 0;
    flags[t] = isbf;
    return;
  }

  // ---- self-classification of this block's source tensor ----
  int wz = (blk - 2048) >> 8;                       // W index (transpose blocks)
  const u16* src = (blk < 2048) ? a0
                 : (wz == 0) ? a1 : (wz == 1) ? a3 : (wz == 2) ? a5 : a7;
  if (t == 0) { cls[0] = 0; cls[1] = 0; cls[2] = 0; }
  __syncthreads();
  if (t < 128) {
    u16 he = src[2*t], ho = src[2*t+1];
    int e = (he >> 7) & 0xff;
    if (he == 0) atomicAdd(&cls[0], 1);
    if (ho != 0) atomicAdd(&cls[1], 1);
    if (he == 0 || (e >= 64 && e <= 160)) atomicAdd(&cls[2], 1);
  }
  __syncthreads();
  int isbf;
  if (cls[0] >= 100 && cls[1] >= 64) isbf = 0;
  else isbf = (cls[2] >= 100) ? 1 : 0;

  if (blk < 2048) {
    // ---- convert x -> bf16 (8 elems/thread) ----
    size_t i = ((size_t)blk * 256 + t) * 8;
    if (isbf) {
      *(float4*)(xb + i) = *((const float4*)(a0 + i));
    } else {
      const float* xf = (const float*)a0;
      float4 a = *(const float4*)(xf + i);
      float4 b = *(const float4*)(xf + i + 4);
      ushort4 o0, o1;
      o0.x = f2bf(a.x); o0.y = f2bf(a.y); o0.z = f2bf(a.z); o0.w = f2bf(a.w);
      o1.x = f2bf(b.x); o1.y = f2bf(b.y); o1.z = f2bf(b.z); o1.w = f2bf(b.w);
      *(ushort4*)(xb + i) = o0; *(ushort4*)(xb + i + 4) = o1;
    }
    return;
  }

  // ---- transpose W[wz]: 64x64 tile (pad 65 => 2-way banks) ----
  {
    int rem = (blk - 2048) & 255;
    int r0 = ((rem >> 4) & 15) * 64, c0 = (rem & 15) * 64;
    u16* dst = wt + (size_t)wz * (1u << 20);
    for (int rr = 0; rr < 2; ++rr) {
      int row = rr * 32 + (t >> 3);
      int c8 = (t & 7) * 8;
      u16 v[8];
      if (isbf) {
        const u16* Ws = src;
        ushort4 a = *(const ushort4*)&Ws[(size_t)(r0 + row) * 1024 + c0 + c8];
        ushort4 b = *(const ushort4*)&Ws[(size_t)(r0 + row) * 1024 + c0 + c8 + 4];
        v[0]=a.x; v[1]=a.y; v[2]=a.z; v[3]=a.w; v[4]=b.x; v[5]=b.y; v[6]=b.z; v[7]=b.w;
      } else {
        const float* Wf = (const float*)src;
        float4 a = *(const float4*)&Wf[(size_t)(r0 + row) * 1024 + c0 + c8];
        float4 b = *(const float4*)&Wf[(size_t)(r0 + row) * 1024 + c0 + c8 + 4];
        v[0]=f2bf(a.x); v[1]=f2bf(a.y); v[2]=f2bf(a.z); v[3]=f2bf(a.w);
        v[4]=f2bf(b.x); v[5]=f2bf(b.y); v[6]=f2bf(b.z); v[7]=f2bf(b.w);
      }
#pragma unroll
      for (int j = 0; j < 8; ++j) tile[row * 65 + c8 + j] = v[j];
    }
    __syncthreads();
    for (int rr = 0; rr < 2; ++rr) {
      int nrow = rr * 32 + (t >> 3);
      int k8 = (t & 7) * 8;
      u16 v[8];
#pragma unroll
      for (int j = 0; j < 8; ++j) v[j] = tile[(k8 + j) * 65 + nrow];
      ushort4 o0, o1;
      o0.x=v[0]; o0.y=v[1]; o0.z=v[2]; o0.w=v[3];
      o1.x=v[4]; o1.y=v[5]; o1.z=v[6]; o1.w=v[7];
      *(ushort4*)&dst[(size_t)(c0 + nrow) * 1024 + r0 + k8] = o0;
      *(ushort4*)&dst[(size_t)(c0 + nrow) * 1024 + r0 + k8 + 4] = o1;
    }
  }
}

// ---------------------------------------------------------------------------
// MTx128-tile gemm_bt: C[m0..m0+MT, n0..n0+128] = A @ Bt^T + bias
// BK=32, TRIPLE-buffered LDS, stage distance 2, counted vmcnt (T4), K-loop
// UNROLLED x3 so the mod-3 buffer index is compile-time (static LDS addrs);
// global stage pointers hoisted (stage adds only ko).
// Loop-top "s_waitcnt vmcnt(N) lgkmcnt(0); s_barrier" in one asm (memory
// clobber): vmcnt(N) waits only the stage about to be read; lgkmcnt(0)
// guards this wave's ds_reads of the buffer the next stage overwrites.
// mode: 0 = fp32 rowmajor, 1 = bf16 rowmajor,
//       2 = bf16 -> vF via LDS-bounce, 3 = bf16 -> kF via LDS-bounce
// Modes 2/3 require MT == 128 (bounce tile T = smem[0..1], 32KB).
// ---------------------------------------------------------------------------
template <int MT>
__device__ __forceinline__ void gemm_bt(const u16* __restrict__ A, const u16* __restrict__ Bt,
    const void* __restrict__ bias, int bias_bf, void* __restrict__ Cout, int mode,
    float cscale, int m0, int n0) {
  constexpr int MI = MT / 32;                             // acc row-tiles per wave
  constexpr int NA = MT / 64;                             // A cp16 per thread/stage
  constexpr int BUFE = (MT + 128) * 32;                   // u16 per buffer
  __shared__ __align__(16) u16 smem[3][BUFE];             // [buf][As MT*32 | Bs 128*32]
  const int tid = threadIdx.x;
  const int wave = tid >> 6, lane = tid & 63;
  const int qd = lane >> 4, ln = lane & 15;
  const int wr = (wave >> 1) * (MT / 2), wc = (wave & 1) * 64;
  const int r0 = wave * 16 + (lane >> 2);
  const int csrc = ((lane & 3) ^ ((lane >> 2) & 3)) * 8;  // swizzled src chunk
  const int co = (qd ^ (ln & 3)) * 8;                     // frag-read chunk
  // hoisted invariant per-thread global stage pointers
  const u16* agp[NA];
  const u16* bgp[2];
#pragma unroll
  for (int t = 0; t < NA; ++t)
    agp[t] = &A[(size_t)(m0 + t * 64 + r0) * 1024 + csrc];
#pragma unroll
  for (int t = 0; t < 2; ++t)
    bgp[t] = &Bt[(size_t)(n0 + t * 64 + r0) * 1024 + csrc];
  f4v acc[MI][4];
#pragma unroll
  for (int i = 0; i < MI; ++i)
#pragma unroll
    for (int j = 0; j < 4; ++j) acc[i][j] = (f4v){0.f, 0.f, 0.f, 0.f};

  // stage K-tile kt into buffer bi (bi compile-time at all call sites)
  auto stage = [&](int kt, int bi) {
    int ko = kt * 32;
#pragma unroll
    for (int t = 0; t < NA; ++t)
      cp16(agp[t] + ko, &smem[bi][(t * 256 + wave * 64) * 8]);
#pragma unroll
    for (int t = 0; t < 2; ++t)
      cp16(bgp[t] + ko, &smem[bi][MT * 32 + (t * 256 + wave * 64) * 8]);
  };

  // prologue: stages 0 and 1 in flight (2*NLOADS outstanding)
  stage(0, 0);
  stage(1, 1);

  for (int itb = 0; itb < 32; itb += 3) {
#pragma unroll
    for (int u = 0; u < 3; ++u) {
      const int it = itb + u;
      if (it >= 32) break;
      // wait stage(it) + this wave's ds_reads, then sync; newest stage's
      // loads stay in flight across the barrier.
      if (it < 31) {
        if constexpr (MT == 128)
          asm volatile("s_waitcnt vmcnt(4) lgkmcnt(0)\n\ts_barrier" ::: "memory");
        else
          asm volatile("s_waitcnt vmcnt(3) lgkmcnt(0)\n\ts_barrier" ::: "memory");
      } else {
        asm volatile("s_waitcnt vmcnt(0) lgkmcnt(0)\n\ts_barrier" ::: "memory");
      }
      if (it + 2 < 32) stage(it + 2, (u + 2) % 3);     // (it+2)%3 == (u+2)%3
      const u16* as = &smem[u][0];                     // it%3 == u
      const u16* bs = &smem[u][MT * 32];
      bf8v af[MI], bfr[4];
#pragma unroll
      for (int i = 0; i < MI; ++i) af[i]  = *(const bf8v*)&as[(wr + i * 16 + ln) * 32 + co];
#pragma unroll
      for (int j = 0; j < 4; ++j) bfr[j] = *(const bf8v*)&bs[(wc + j * 16 + ln) * 32 + co];
#pragma unroll
      for (int i = 0; i < MI; ++i)
#pragma unroll
        for (int j = 0; j < 4; ++j)
          acc[i][j] = __builtin_amdgcn_mfma_f32_16x16x32_bf16(af[i], bfr[j], acc[i][j], 0, 0, 0);
    }
  }

  if (mode == 2 || mode == 3) {
    // ---- LDS-bounce epilogue: T[token_local][feat_local] 128x128 bf16 ----
    if constexpr (MT == 128) {
      __syncthreads();                     // drain + all waves done with smem
      u16* T = &smem[0][0];                // 16384 u16 = 32KB (bufs 0+1)
      float bvs[4];
#pragma unroll
      for (int j = 0; j < 4; ++j) {
        int col = n0 + wc + j * 16 + ln;
        bvs[j] = bias_bf ? bf2f(((const u16*)bias)[col]) : ((const float*)bias)[col];
      }
#pragma unroll
      for (int i = 0; i < MI; ++i)
#pragma unroll
        for (int j = 0; j < 4; ++j)
#pragma unroll
          for (int r = 0; r < 4; ++r)
            T[(wr + i * 16 + qd * 4 + r) * 128 + (wc + j * 16 + ln)] =
                f2bf((acc[i][j][r] + bvs[j]) * cscale);
      __syncthreads();
      const int b_ = m0 >> 11, nl0 = m0 & 2047;
      const int tg0 = nl0 >> 6, h0 = n0 >> 6;
      u16* outp = (u16*)Cout;
#pragma unroll
      for (int pass = 0; pass < 8; ++pass) {
        int u = pass * 256 + tid;          // 2048 units of 16B
        int c2 = u >> 9, w = u & 511;
        int f = w >> 6, l = w & 63;
        int tt = c2 >> 1, hh = c2 & 1;     // token-tile half, head half
        u16* dstp = outp + (size_t)(b_ * 16 + h0 + hh) * 131072
                  + (size_t)(tg0 + tt) * 4096 + f * 512 + l * 8;
        if (mode == 3) {
          // kF: frag f=(ct*2+half), lane l=(qdk*16+lnk), jj = 8 consec feats
          int ct = f >> 1, half = f & 1, qdk = l >> 4, lnk = l & 15;
          int tok = tt * 64 + ct * 16 + lnk;
          int feat = hh * 64 + half * 32 + qdk * 8;
          *(bf8v*)dstp = *(const bf8v*)&T[tok * 128 + feat];
        } else {
          // vF: frag f=(c*4+dt), lane l=(qdf*16+lnf), jj=(g*4+r) token slots
          int c = f >> 2, dt = f & 3, qdf = l >> 4, lnf = l & 15;
          int featl = hh * 64 + dt * 16 + lnf;
          u16 vals[8];
#pragma unroll
          for (int jj = 0; jj < 8; ++jj) {
            int tokl = tt * 64 + c * 32 + (jj >> 2) * 16 + qdf * 4 + (jj & 3);
            vals[jj] = T[tokl * 128 + featl];
          }
          bf8v vv; __builtin_memcpy(&vv, vals, 16);
          *(bf8v*)dstp = vv;
        }
      }
    }
    return;
  }

  // ---- row-major epilogue (modes 0/1): C row = m0+wr+i*16+qd*4+r ----
#pragma unroll
  for (int j = 0; j < 4; ++j) {
    int col = n0 + wc + j * 16 + ln;
    float bv = bias_bf ? bf2f(((const u16*)bias)[col]) : ((const float*)bias)[col];
#pragma unroll
    for (int i = 0; i < MI; ++i) {
      int row = m0 + wr + i * 16 + qd * 4;
#pragma unroll
      for (int r = 0; r < 4; ++r) {
        float v = (acc[i][j][r] + bv) * cscale;
        if (mode == 1) ((u16*)Cout)[(size_t)(row + r) * 1024 + col] = f2bf(v);
        else           ((float*)Cout)[(size_t)(row + r) * 1024 + col] = v;
      }
    }
  }
}

// 1D grid 768, XCD-chunk swizzled: HW XCD = id%8. XCD k owns y-chunk (k>>1)
// (8 m-tiles) x x-chunk (k&1) (4 n-tiles) x all z. Within-XCD order: x
// innermost, then z, then y -> 12 consecutive blocks share one A panel.
__global__ __launch_bounds__(256) void k_gemm_qkv(const u16* xb, const u16* wt,
    const void* bq, const void* bk, const void* bv, const int* flags,
    u16* qpre, u16* kb, u16* vtb) {
  const int id = blockIdx.x;
  const int xcd = id & 7, j = id >> 3;    // j in [0,96)
  const int xw = j & 3, jj = j >> 2;      // jj in [0,24)
  const int z = jj % 3, yw = jj / 3;      // yw in [0,8)
  const int y = (xcd >> 1) * 8 + yw;      // m-tile in [0,32)
  const int x = (xcd & 1) * 4 + xw;       // n-tile in [0,8)
  const u16* Bt = wt + (size_t)z * (1u << 20);
  const void* bias = (z == 0) ? bq : (z == 1) ? bk : bv;
  if (z == 0)      gemm_bt<128>(xb, Bt, bias, flags[2], qpre, 1, 1.0f,   y * 128, x * 128);
  else if (z == 1) gemm_bt<128>(xb, Bt, bias, flags[4], kb,   3, KSCALE, y * 128, x * 128);
  else             gemm_bt<128>(xb, Bt, bias, flags[6], vtb,  2, 1.0f,   y * 128, x * 128);
}

// 1D grid 512, same swizzle idea: XCD k owns y-chunk (k>>1) (16 m-tiles of
// 64) x x-chunk (k&1) (4 n-tiles).
__global__ __launch_bounds__(256) void k_gemm_out(const u16* A, const u16* Bt,
    const void* bias, const int* flags, void* out) {
  const int id = blockIdx.x;
  const int xcd = id & 7, j = id >> 3;    // j in [0,64)
  const int xw = j & 3, yw = j >> 2;      // yw in [0,16)
  const int y = (xcd >> 1) * 16 + yw;     // m-tile in [0,64)
  const int x = (xcd & 1) * 4 + xw;       // n-tile in [0,8)
  gemm_bt<64>(A, Bt, bias, flags[8], out, flags[0] ? 1 : 0, 1.0f, y * 64, x * 128);
}

// ---------------------------------------------------------------------------
// LayerNorm over rows of 1024: block per row, 256 threads x 4 elems.
// (Separate-kernel form: fusing LN into attention cost ~10us — R21/R22.)
// ---------------------------------------------------------------------------
__global__ __launch_bounds__(256) void k_layernorm(const u16* __restrict__ qp,
    const void* __restrict__ g, const void* __restrict__ bb, const int* flags,
    u16* __restrict__ out) {
  int row = blockIdx.x, t = threadIdx.x;
  const u16* rp = qp + (size_t)row * 1024;
  ushort4 u = *(const ushort4*)(rp + t * 4);
  float x0 = bf2f(u.x), x1 = bf2f(u.y), x2 = bf2f(u.z), x3 = bf2f(u.w);
  float s = x0 + x1 + x2 + x3;
  float s2 = x0 * x0 + x1 * x1 + x2 * x2 + x3 * x3;
  for (int off = 32; off; off >>= 1) { s += __shfl_down(s, off); s2 += __shfl_down(s2, off); }
  __shared__ float red[10];
  int wave = t >> 6, lane = t & 63;
  if (lane == 0) { red[wave] = s; red[4 + wave] = s2; }
  __syncthreads();
  if (t == 0) {
    float S = red[0] + red[1] + red[2] + red[3];
    float S2 = red[4] + red[5] + red[6] + red[7];
    float mu = S * (1.f / 1024.f);
    float var = S2 * (1.f / 1024.f) - mu * mu;
    red[8] = mu; red[9] = rsqrtf(var + 1e-5f);
  }
  __syncthreads();
  float mu = red[8], rstd = red[9];
  int gf = flags[9], bf = flags[10];
  int c = t * 4;
  float gv[4], bv[4];
#pragma unroll
  for (int k = 0; k < 4; ++k) {
    gv[k] = gf ? bf2f(((const u16*)g)[c + k]) : ((const float*)g)[c + k];
    bv[k] = bf ? bf2f(((const u16*)bb)[c + k]) : ((const float*)bb)[c + k];
  }
  ushort4 o;
  o.x = f2bf((x0 - mu) * rstd * gv[0] + bv[0]);
  o.y = f2bf((x1 - mu) * rstd * gv[1] + bv[1]);
  o.z = f2bf((x2 - mu) * rstd * gv[2] + bv[2]);
  o.w = f2bf((x3 - mu) * rstd * gv[3] + bv[3]);
  *(ushort4*)(out + (size_t)row * 1024 + c) = o;
}

// ---------------------------------------------------------------------------
// One-tile attention compute from LDS-resident fragments (all static idx).
// ---------------------------------------------------------------------------
template <int NQS>
__device__ __forceinline__ void attn_tile(const bf8v kf[4][2], const bf8v vf[8],
    const bf8v qf[NQS][2], float ls[NQS][4], f4v o[NQS][4]) {
#pragma unroll
  for (int qs = 0; qs < NQS; ++qs) {
    unsigned pk[4][2];
#pragma unroll
    for (int ct = 0; ct < 4; ++ct) {
      f4v z = (f4v){0.f, 0.f, 0.f, 0.f};
      z = __builtin_amdgcn_mfma_f32_16x16x32_bf16(kf[ct][0], qf[qs][0], z, 0, 0, 0);  // S^T
      z = __builtin_amdgcn_mfma_f32_16x16x32_bf16(kf[ct][1], qf[qs][1], z, 0, 0, 0);
      float p0 = __builtin_amdgcn_exp2f(z[0]);
      float p1 = __builtin_amdgcn_exp2f(z[1]);
      float p2 = __builtin_amdgcn_exp2f(z[2]);
      float p3 = __builtin_amdgcn_exp2f(z[3]);
      ls[qs][0] += p0; ls[qs][1] += p1; ls[qs][2] += p2; ls[qs][3] += p3;
      pk[ct][0] = pack2bf(p0, p1);
      pk[ct][1] = pack2bf(p2, p3);
    }
#pragma unroll
    for (int c = 0; c < 2; ++c) {
      unsigned avals[4] = {pk[2*c][0], pk[2*c][1], pk[2*c+1][0], pk[2*c+1][1]};
      bf8v af; __builtin_memcpy(&af, avals, 16);
#pragma unroll
      for (int dt = 0; dt < 4; ++dt)
        o[qs][dt] = __builtin_amdgcn_mfma_f32_16x16x32_bf16(af, vf[c * 4 + dt], o[qs][dt], 0, 0, 0);
    }
  }
}

// ---------------------------------------------------------------------------
// Flash attention (R24 form, measured floor ~47us): 256-thread blocks (4
// waves), each wave 32 q-rows. KVBLK=128: two 64-key tiles staged per
// barrier (16 barriers); LDS 64KB/block, 2 blocks/CU. setprio(1) wraps
// tile-compute. Grid 512 = XCD slot x 4 bh x 16 q-chunks; residual fused.
// ---------------------------------------------------------------------------
__global__ __launch_bounds__(256) void k_attention(const u16* __restrict__ qln,
    const u16* __restrict__ kfg, const u16* __restrict__ vfg, u16* __restrict__ attn) {
  const int x = blockIdx.x;
  const int xcd = x & 7, sl = x >> 3;                // sl in [0,64)
  const int bh = xcd * 4 + (sl >> 4), qc = sl & 15;  // 4 bh per XCD slot, 16 q-chunks
  const int b = bh >> 4, h = bh & 15;
  const int tid = threadIdx.x, wave = tid >> 6, lane = tid & 63;
  const int qd = lane >> 4, ln = lane & 15;
  const int qrow0 = qc * 128 + wave * 32;            // this wave's 32 q-rows

  const u16* kgb = kfg + (size_t)bh * 131072;        // kF fragment-ordered
  const u16* vgb = vfg + (size_t)bh * 131072;        // vF fragment-ordered

  __shared__ __align__(16) u16 kv[2][16384];         // [buf][K-pair 8192 | V-pair 8192]

  bf8v qf[2][2];
#pragma unroll
  for (int qs = 0; qs < 2; ++qs) {
    const u16* qb = qln + ((size_t)b * 2048 + qrow0 + qs * 16 + ln) * 1024 + h * 64;
    qf[qs][0] = *(const bf8v*)(qb + qd * 8);
    qf[qs][1] = *(const bf8v*)(qb + 32 + qd * 8);
  }
  float ls[2][4];
  f4v o[2][4];
#pragma unroll
  for (int qs = 0; qs < 2; ++qs)
#pragma unroll
    for (int r = 0; r < 4; ++r) { ls[qs][r] = 0.f; o[qs][r] = (f4v){0.f, 0.f, 0.f, 0.f}; }

  // prologue: stage tile-pair 0 (tiles 0,1) into buf 0: 8 cp16/thread = 32KB
#pragma unroll
  for (int q = 0; q < 4; ++q) {
    cp16(kgb + (size_t)(q * 256 + tid) * 8, &kv[0][(q * 256 + wave * 64) * 8]);
    cp16(vgb + (size_t)(q * 256 + tid) * 8, &kv[0][8192 + (q * 256 + wave * 64) * 8]);
  }

  for (int tp = 0; tp < 16; ++tp) {
    __syncthreads();                                 // drains stage(tp)
    if (tp < 15) {
      const u16* ks = kgb + (size_t)(tp + 1) * 8192;
      const u16* vs = vgb + (size_t)(tp + 1) * 8192;
      u16* dst = kv[(tp + 1) & 1];
#pragma unroll
      for (int q = 0; q < 4; ++q) {
        cp16(ks + (size_t)(q * 256 + tid) * 8, &dst[(q * 256 + wave * 64) * 8]);
        cp16(vs + (size_t)(q * 256 + tid) * 8, &dst[8192 + (q * 256 + wave * 64) * 8]);
      }
    }
    const u16* kvb = kv[tp & 1];
#pragma unroll
    for (int s = 0; s < 2; ++s) {                    // two 64-key tiles per pair
      const u16* kp = kvb + s * 4096;
      const u16* vp = kvb + 8192 + s * 4096;
      bf8v kfr[4][2], vfr[8];
#pragma unroll
      for (int ct = 0; ct < 4; ++ct) {
        kfr[ct][0] = *(const bf8v*)&kp[(ct * 2 + 0) * 512 + lane * 8];
        kfr[ct][1] = *(const bf8v*)&kp[(ct * 2 + 1) * 512 + lane * 8];
      }
#pragma unroll
      for (int cd = 0; cd < 8; ++cd)
        vfr[cd] = *(const bf8v*)&vp[cd * 512 + lane * 8];
      __builtin_amdgcn_s_setprio(1);
      attn_tile<2>(kfr, vfr, qf, ls, o);
      __builtin_amdgcn_s_setprio(0);
    }
  }

  // per q-subtile: reduce den (2 shuffles), store with fused residual
#pragma unroll
  for (int qs = 0; qs < 2; ++qs) {
    float lsum = (ls[qs][0] + ls[qs][1]) + (ls[qs][2] + ls[qs][3]);
    lsum += __shfl_xor(lsum, 16);
    lsum += __shfl_xor(lsum, 32);                     // den[q=ln] on every lane
    float rden[4];
#pragma unroll
    for (int r = 0; r < 4; ++r) {
      float dv = __shfl(lsum, (lane & 48) + qd * 4 + r);  // lane with ln=qd*4+r
      rden[r] = __builtin_amdgcn_rcpf(1e-8f + dv);
    }
#pragma unroll
    for (int dt = 0; dt < 4; ++dt) {
#pragma unroll
      for (int r = 0; r < 4; ++r) {
        size_t idx = ((size_t)b * 2048 + qrow0 + qs * 16 + qd * 4 + r) * 1024
                   + h * 64 + dt * 16 + ln;
        float val = o[qs][dt][r] * rden[r] + bf2f(qln[idx]);
        attn[idx] = f2bf(val);
      }
    }
  }
}

// ---------------------------------------------------------------------------
extern "C" void kernel_launch(void* const* d_in, const int* in_sizes, int n_in,
                              void* d_out, int out_size, void* d_ws, size_t ws_size,
                              hipStream_t stream) {
  // inputs: 0:x 1:Wq 2:bq 3:Wk 4:bk 5:Wv 6:bv 7:Wo 8:bo 9:ln_g 10:ln_b
  int* flags = (int*)d_ws;
  u16* base = (u16*)((char*)d_ws + 256);
  const size_t M1 = 1u << 20;
  u16* xb   = base;            // x bf16; overwritten by qln after gemm_qkv
  u16* wt   = base + 4 * M1;   // Wq^T,Wk^T,Wv^T,Wo^T (4 x 1M)
  u16* qpre = base + 8 * M1;   // q pre-LN; reused as attn-out after LN
  u16* kb   = base + 12 * M1;  // kF fragment-ordered K (pre-scaled by KSCALE)
  u16* vtb  = base + 16 * M1;  // vF fragment-ordered V (written by V-GEMM)
  u16* qln = xb;
  u16* at  = qpre;

  k_preprocess<<<3073, 256, 0, stream>>>(
      (const u16*)d_in[0], (const u16*)d_in[1], (const u16*)d_in[2], (const u16*)d_in[3],
      (const u16*)d_in[4], (const u16*)d_in[5], (const u16*)d_in[6], (const u16*)d_in[7],
      (const u16*)d_in[8], (const u16*)d_in[9], (const u16*)d_in[10], xb, wt, flags);
  k_gemm_qkv<<<768, 256, 0, stream>>>(xb, wt, d_in[2], d_in[4], d_in[6], flags,
                                      qpre, kb, vtb);
  k_layernorm<<<4096, 256, 0, stream>>>(qpre, d_in[9], d_in[10], flags, qln);
  k_attention<<<512, 256, 0, stream>>>(qln, kb, vtb, at);
  k_gemm_out<<<512, 256, 0, stream>>>(at, wt + 3 * M1, d_in[8], flags, d_out);
}